// Round 3
// baseline (4328.609 us; speedup 1.0000x reference)
//
#include <hip/hip_runtime.h>
#include <math.h>

// Problem constants
#define D_MODEL 1024
#define D_STATE 16
#define D_CONVK 4
#define D_INNER 2048
#define DT_RANK 64
#define MLP_HID 2048
#define BB 4
#define LL 2048
#define NTOK (BB * LL)  // 8192

typedef unsigned short bf16_t;

// ---------------- dtype helpers ----------------
__device__ __forceinline__ float b2f(bf16_t u) {
    return __uint_as_float(((unsigned int)u) << 16);
}
__device__ __forceinline__ bf16_t f2b(float f) {
    unsigned int x = __float_as_uint(f);
    unsigned int r = (x + 0x7FFFu + ((x >> 16) & 1u)) >> 16;
    return (bf16_t)r;
}
__device__ __forceinline__ void ld4(const float* p, float v[4]) {
    const float4 t = *(const float4*)p;
    v[0] = t.x; v[1] = t.y; v[2] = t.z; v[3] = t.w;
}
__device__ __forceinline__ void ld4(const bf16_t* p, float v[4]) {
    const ushort4 t = *(const ushort4*)p;
    v[0] = b2f(t.x); v[1] = b2f(t.y); v[2] = b2f(t.z); v[3] = b2f(t.w);
}
__device__ __forceinline__ float ld1(const float* p) { return *p; }
__device__ __forceinline__ float ld1(const bf16_t* p) { return b2f(*p); }
__device__ __forceinline__ void st4(float* p, const float v[4]) {
    *(float4*)p = make_float4(v[0], v[1], v[2], v[3]);
}
__device__ __forceinline__ void st4(bf16_t* p, const float v[4]) {
    *(ushort4*)p = make_ushort4(f2b(v[0]), f2b(v[1]), f2b(v[2]), f2b(v[3]));
}

__device__ __forceinline__ float sigmoidf_(float x) { return 1.0f / (1.0f + __expf(-x)); }
__device__ __forceinline__ float siluf_(float x) { return x * sigmoidf_(x); }
__device__ __forceinline__ float softplusf_(float x) {
    return (x > 20.0f) ? x : log1pf(expf(x));
}
__device__ __forceinline__ float geluf_(float x) {
    return 0.5f * x * (1.0f + erff(x * 0.7071067811865475f));
}

// ---------------- LayerNorm (row = 1024): T in, bf16 out ----------------
template <typename T>
__launch_bounds__(256)
__global__ void ln_kernel(const T* __restrict__ x, const float* __restrict__ g,
                          const float* __restrict__ b, bf16_t* __restrict__ out) {
    const int row = blockIdx.x;
    float v[4];
    ld4(x + (size_t)row * D_MODEL + threadIdx.x * 4, v);
    float s = v[0] + v[1] + v[2] + v[3];
    float s2 = v[0] * v[0] + v[1] * v[1] + v[2] * v[2] + v[3] * v[3];
    for (int off = 32; off > 0; off >>= 1) {
        s += __shfl_down(s, off);
        s2 += __shfl_down(s2, off);
    }
    __shared__ float ls[4], ls2[4];
    const int wid = threadIdx.x >> 6;
    if ((threadIdx.x & 63) == 0) { ls[wid] = s; ls2[wid] = s2; }
    __syncthreads();
    const float ts = ls[0] + ls[1] + ls[2] + ls[3];
    const float ts2 = ls2[0] + ls2[1] + ls2[2] + ls2[3];
    const float mean = ts * (1.0f / D_MODEL);
    const float var = ts2 * (1.0f / D_MODEL) - mean * mean;
    const float inv = rsqrtf(var + 1e-5f);
    float gg[4], bb[4], o[4];
    ld4(g + threadIdx.x * 4, gg);
    ld4(b + threadIdx.x * 4, bb);
    for (int i = 0; i < 4; ++i) o[i] = (v[i] - mean) * inv * gg[i] + bb[i];
    st4(out + (size_t)row * D_MODEL + threadIdx.x * 4, o);
}

// ---------------- GEMM: out[M,N] = A[M,K(lda)] @ W[N,K]^T (+epilogue) ----------
// A bf16, W/bias fp32, res type RT, out type OT; fp32 accumulate.
// EPI: 0=none, 1=bias+softplus, 2=bias+gelu, 3=+res, 4=bias+res
template <int EPI, typename RT, typename OT>
__launch_bounds__(256)
__global__ void gemm_kernel(const bf16_t* __restrict__ A, int lda,
                            const float* __restrict__ W,
                            const float* __restrict__ bias,
                            const RT* __restrict__ res,
                            OT* __restrict__ out,
                            int M, int N, int K) {
    __shared__ float As[16][68];
    __shared__ float Ws[16][68];
    const int bm = blockIdx.y * 64;
    const int bn = blockIdx.x * 64;
    const int tx = threadIdx.x & 15;
    const int ty = threadIdx.x >> 4;
    const int lr = threadIdx.x >> 2;         // 0..63 (tile row)
    const int lc = (threadIdx.x & 3) << 2;   // 0,4,8,12 (k offset)
    float acc[4][4] = {{0.f}};
    const bf16_t* Aptr = A + (size_t)(bm + lr) * lda + lc;
    const float* Wptr = W + (size_t)(bn + lr) * K + lc;
    const bool wvalid = (bn + lr) < N;

    for (int k0 = 0; k0 < K; k0 += 16) {
        float a4[4], w4[4] = {0.f, 0.f, 0.f, 0.f};
        ld4(Aptr + k0, a4);
        if (wvalid) ld4(Wptr + k0, w4);
        __syncthreads();
        As[lc + 0][lr] = a4[0]; As[lc + 1][lr] = a4[1];
        As[lc + 2][lr] = a4[2]; As[lc + 3][lr] = a4[3];
        Ws[lc + 0][lr] = w4[0]; Ws[lc + 1][lr] = w4[1];
        Ws[lc + 2][lr] = w4[2]; Ws[lc + 3][lr] = w4[3];
        __syncthreads();
#pragma unroll
        for (int k = 0; k < 16; ++k) {
            float a[4], w[4];
#pragma unroll
            for (int i = 0; i < 4; ++i) a[i] = As[k][(ty << 2) + i];
#pragma unroll
            for (int j = 0; j < 4; ++j) w[j] = Ws[k][(tx << 2) + j];
#pragma unroll
            for (int i = 0; i < 4; ++i)
#pragma unroll
                for (int j = 0; j < 4; ++j) acc[i][j] = fmaf(a[i], w[j], acc[i][j]);
        }
    }

#pragma unroll
    for (int i = 0; i < 4; ++i) {
        const int row = bm + (ty << 2) + i;
        const int col0 = bn + (tx << 2);
        if (col0 < N) {
            float vv[4];
#pragma unroll
            for (int j = 0; j < 4; ++j) {
                float v = acc[i][j];
                const int col = col0 + j;
                if (EPI == 1 || EPI == 2 || EPI == 4) v += bias[col];
                if (EPI == 1) v = softplusf_(v);
                if (EPI == 2) v = geluf_(v);
                if (EPI == 3 || EPI == 4) v += ld1(res + (size_t)row * N + col);
                vv[j] = v;
            }
            st4(out + (size_t)row * N + col0, vv);
        }
    }
}

// ---------------- causal depthwise conv (k=4) + SiLU ----------------
__launch_bounds__(256)
__global__ void conv_silu_kernel(const bf16_t* __restrict__ xm, const float* __restrict__ cw,
                                 const float* __restrict__ cb, bf16_t* __restrict__ xa) {
    const int idx = blockIdx.x * 256 + threadIdx.x;  // over NTOK * D_INNER
    const int d = idx & (D_INNER - 1);
    const int bt = idx >> 11;
    const int t = bt & (LL - 1);
    const int b = bt >> 11;
    float acc = cb[d];
#pragma unroll
    for (int k = 0; k < D_CONVK; ++k) {
        const int tt = t - 3 + k;
        if (tt >= 0) {
            acc += b2f(xm[((size_t)(b * LL + tt)) * D_INNER + d]) * cw[d * D_CONVK + k];
        }
    }
    xa[(size_t)idx] = f2b(siluf_(acc));
}

// ---------------- selective scan ----------------
// thread = (channel c 0..15) x (state n 0..15); y written in place over xa.
__launch_bounds__(256)
__global__ void scan_kernel(const bf16_t* __restrict__ delta,
                            bf16_t* __restrict__ xa,
                            const bf16_t* __restrict__ xdbl,
                            const bf16_t* __restrict__ z,
                            const float* __restrict__ A_log,
                            const float* __restrict__ Dp) {
    const int b = blockIdx.x >> 7;            // 4 b x 128 d-tiles
    const int d0 = (blockIdx.x & 127) << 4;
    const int c = threadIdx.x >> 4;
    const int n = threadIdx.x & 15;
    const int d = d0 + c;
    const float Acoef = -expf(A_log[d * D_STATE + n]);
    const float Dd = Dp[d];
    float h = 0.f;
    const bf16_t* dptr = delta + (size_t)b * LL * D_INNER + d;
    bf16_t* uptr = xa + (size_t)b * LL * D_INNER + d;
    const bf16_t* bcp = xdbl + (size_t)b * LL * 96;
    const bf16_t* zptr = z + (size_t)b * LL * D_INNER + d;
    for (int t = 0; t < LL; ++t) {
        const float dlt = b2f(dptr[(size_t)t * D_INNER]);
        const float u = b2f(uptr[(size_t)t * D_INNER]);
        const float Bv = b2f(bcp[(size_t)t * 96 + DT_RANK + n]);
        const float Cv = b2f(bcp[(size_t)t * 96 + DT_RANK + D_STATE + n]);
        const float dA = __expf(dlt * Acoef);
        h = h * dA + dlt * u * Bv;
        float yv = h * Cv;
        yv += __shfl_xor(yv, 1);
        yv += __shfl_xor(yv, 2);
        yv += __shfl_xor(yv, 4);
        yv += __shfl_xor(yv, 8);
        if (n == 0) {
            const float zz = b2f(zptr[(size_t)t * D_INNER]);
            uptr[(size_t)t * D_INNER] = f2b((yv + u * Dd) * siluf_(zz));
        }
    }
}

// ---------------- launch ----------------
extern "C" void kernel_launch(void* const* d_in, const int* in_sizes, int n_in,
                              void* d_out, int out_size, void* d_ws, size_t ws_size,
                              hipStream_t stream) {
    const float* x         = (const float*)d_in[0];
    const float* ln1_g     = (const float*)d_in[1];
    const float* ln1_b     = (const float*)d_in[2];
    const float* in_proj_w = (const float*)d_in[3];
    const float* conv_w    = (const float*)d_in[4];
    const float* conv_b    = (const float*)d_in[5];
    const float* x_proj_w  = (const float*)d_in[6];
    const float* dt_proj_w = (const float*)d_in[7];
    const float* dt_proj_b = (const float*)d_in[8];
    const float* A_log     = (const float*)d_in[9];
    const float* Dp        = (const float*)d_in[10];
    const float* out_proj_w= (const float*)d_in[11];
    const float* ln2_g     = (const float*)d_in[12];
    const float* ln2_b     = (const float*)d_in[13];
    const float* mlp_w1    = (const float*)d_in[14];
    const float* mlp_b1    = (const float*)d_in[15];
    const float* mlp_w2    = (const float*)d_in[16];
    const float* mlp_b2    = (const float*)d_in[17];
    float* outp = (float*)d_out;

    // workspace layout (bf16 elems); total 67,895,296 elems = ~136 MB
    bf16_t* ws   = (bf16_t*)d_ws;
    bf16_t* h    = ws;               //  8,388,608  (NTOK x 1024)  later: h2
    bf16_t* xm   = ws + 8388608;     // 16,777,216  (NTOK x 2048)  later: delta
    bf16_t* z    = ws + 25165824;    // 16,777,216  (NTOK x 2048)  later: m1
    bf16_t* xa   = ws + 41943040;    // 16,777,216  (NTOK x 2048)  later: y (in-place)
    bf16_t* xdbl = ws + 58720256;    //    786,432  (NTOK x 96)
    bf16_t* xres = ws + 59506688;    //  8,388,608  (NTOK x 1024)
    bf16_t* delta = xm;
    bf16_t* h2    = h;
    bf16_t* m1    = z;
    bf16_t* y     = xa;

    // 1. LN1 (fp32 in)
    ln_kernel<float><<<NTOK, 256, 0, stream>>>(x, ln1_g, ln1_b, h);
    // 2a. in_proj (x half): xm = h @ in_proj_w[0:2048].T
    gemm_kernel<0, float, bf16_t><<<dim3(D_INNER / 64, NTOK / 64), 256, 0, stream>>>(
        h, D_MODEL, in_proj_w, nullptr, (const float*)nullptr, xm, NTOK, D_INNER, D_MODEL);
    // 2b. in_proj (z half): z = h @ in_proj_w[2048:4096].T
    gemm_kernel<0, float, bf16_t><<<dim3(D_INNER / 64, NTOK / 64), 256, 0, stream>>>(
        h, D_MODEL, in_proj_w + (size_t)D_INNER * D_MODEL, nullptr, (const float*)nullptr, z,
        NTOK, D_INNER, D_MODEL);
    // 3. conv + silu -> xa
    conv_silu_kernel<<<(NTOK * D_INNER) / 256, 256, 0, stream>>>(xm, conv_w, conv_b, xa);
    // 4. x_proj: x_dbl = xa @ x_proj_w.T (8192 x 96, K=2048)
    gemm_kernel<0, float, bf16_t><<<dim3(2, NTOK / 64), 256, 0, stream>>>(
        xa, D_INNER, x_proj_w, nullptr, (const float*)nullptr, xdbl, NTOK, 96, D_INNER);
    // 5. dt_proj + softplus: delta = softplus(x_dbl[:, :64] @ dt_proj_w.T + b)
    gemm_kernel<1, float, bf16_t><<<dim3(D_INNER / 64, NTOK / 64), 256, 0, stream>>>(
        xdbl, 96, dt_proj_w, dt_proj_b, (const float*)nullptr, delta, NTOK, D_INNER, DT_RANK);
    // 6. selective scan (+ u*D, * silu(z)) -> y (in place over xa)
    scan_kernel<<<BB * (D_INNER / 16), 256, 0, stream>>>(delta, xa, xdbl, z, A_log, Dp);
    // 7. out_proj + residual x (fp32) -> xres
    gemm_kernel<3, float, bf16_t><<<dim3(D_MODEL / 64, NTOK / 64), 256, 0, stream>>>(
        y, D_INNER, out_proj_w, nullptr, x, xres, NTOK, D_MODEL, D_INNER);
    // 8. LN2 (bf16 in)
    ln_kernel<bf16_t><<<NTOK, 256, 0, stream>>>(xres, ln2_g, ln2_b, h2);
    // 9. mlp1 + gelu
    gemm_kernel<2, float, bf16_t><<<dim3(MLP_HID / 64, NTOK / 64), 256, 0, stream>>>(
        h2, D_MODEL, mlp_w1, mlp_b1, (const float*)nullptr, m1, NTOK, MLP_HID, D_MODEL);
    // 10. mlp2 + bias + residual xres -> out (fp32)
    gemm_kernel<4, bf16_t, float><<<dim3(D_MODEL / 64, NTOK / 64), 256, 0, stream>>>(
        m1, MLP_HID, mlp_w2, mlp_b2, xres, outp, NTOK, D_MODEL, MLP_HID);
}

// Round 4
// 1607.572 us; speedup vs baseline: 2.6926x; 2.6926x over previous
//
#include <hip/hip_runtime.h>
#include <math.h>

// Problem constants
#define D_MODEL 1024
#define D_STATE 16
#define D_CONVK 4
#define D_INNER 2048
#define DT_RANK 64
#define MLP_HID 2048
#define BB 4
#define LL 2048
#define NTOK (BB * LL)  // 8192

typedef unsigned short bf16_t;
typedef __attribute__((ext_vector_type(8))) short short8v;   // 8 bf16 (4 VGPRs)
typedef __attribute__((ext_vector_type(4))) float float4v;   // 4 fp32 acc

// ---------------- dtype helpers ----------------
__device__ __forceinline__ float b2f(bf16_t u) {
    return __uint_as_float(((unsigned int)u) << 16);
}
__device__ __forceinline__ bf16_t f2b(float f) {
    unsigned int x = __float_as_uint(f);
    unsigned int r = (x + 0x7FFFu + ((x >> 16) & 1u)) >> 16;
    return (bf16_t)r;
}
__device__ __forceinline__ void ld4(const float* p, float v[4]) {
    const float4 t = *(const float4*)p;
    v[0] = t.x; v[1] = t.y; v[2] = t.z; v[3] = t.w;
}
__device__ __forceinline__ void ld4(const bf16_t* p, float v[4]) {
    const ushort4 t = *(const ushort4*)p;
    v[0] = b2f(t.x); v[1] = b2f(t.y); v[2] = b2f(t.z); v[3] = b2f(t.w);
}
__device__ __forceinline__ float ld1(const float* p) { return *p; }
__device__ __forceinline__ float ld1(const bf16_t* p) { return b2f(*p); }
__device__ __forceinline__ void st1(float* p, float v) { *p = v; }
__device__ __forceinline__ void st1(bf16_t* p, float v) { *p = f2b(v); }
__device__ __forceinline__ void st4(bf16_t* p, const float v[4]) {
    *(ushort4*)p = make_ushort4(f2b(v[0]), f2b(v[1]), f2b(v[2]), f2b(v[3]));
}

__device__ __forceinline__ float sigmoidf_(float x) { return 1.0f / (1.0f + __expf(-x)); }
__device__ __forceinline__ float siluf_(float x) { return x * sigmoidf_(x); }
__device__ __forceinline__ float softplusf_(float x) {
    return (x > 20.0f) ? x : log1pf(expf(x));
}
__device__ __forceinline__ float geluf_(float x) {
    return 0.5f * x * (1.0f + erff(x * 0.7071067811865475f));
}

// async global->LDS, 16B per lane (dest = wave-uniform base + lane*16)
__device__ __forceinline__ void gload_lds16(const bf16_t* g, bf16_t* l) {
    __builtin_amdgcn_global_load_lds(
        (__attribute__((address_space(1))) void*)(g),
        (__attribute__((address_space(3))) void*)(l), 16, 0, 0);
}

// ---------------- weight fp32 -> bf16 convert ----------------
__launch_bounds__(256)
__global__ void wconv_kernel(const float* __restrict__ src, bf16_t* __restrict__ dst, int n) {
    const int i = (blockIdx.x * 256 + threadIdx.x) * 4;
    if (i < n) {
        float v[4];
        ld4(src + i, v);
        st4(dst + i, v);
    }
}

// x_proj pad: dst is 128 x 2048 bf16, src is 96 x 2048 fp32, rows 96..127 zero
__launch_bounds__(256)
__global__ void xproj_pad_kernel(const float* __restrict__ src, bf16_t* __restrict__ dst) {
    const int i = (blockIdx.x * 256 + threadIdx.x) * 4;  // over 128*2048
    float v[4] = {0.f, 0.f, 0.f, 0.f};
    if (i < 96 * 2048) ld4(src + i, v);
    st4(dst + i, v);
}

// ---------------- LayerNorm (row = 1024): T in, bf16 out ----------------
template <typename T>
__launch_bounds__(256)
__global__ void ln_kernel(const T* __restrict__ x, const float* __restrict__ g,
                          const float* __restrict__ b, bf16_t* __restrict__ out) {
    const int row = blockIdx.x;
    float v[4];
    ld4(x + (size_t)row * D_MODEL + threadIdx.x * 4, v);
    float s = v[0] + v[1] + v[2] + v[3];
    float s2 = v[0] * v[0] + v[1] * v[1] + v[2] * v[2] + v[3] * v[3];
    for (int off = 32; off > 0; off >>= 1) {
        s += __shfl_down(s, off);
        s2 += __shfl_down(s2, off);
    }
    __shared__ float ls[4], ls2[4];
    const int wid = threadIdx.x >> 6;
    if ((threadIdx.x & 63) == 0) { ls[wid] = s; ls2[wid] = s2; }
    __syncthreads();
    const float ts = ls[0] + ls[1] + ls[2] + ls[3];
    const float ts2 = ls2[0] + ls2[1] + ls2[2] + ls2[3];
    const float mean = ts * (1.0f / D_MODEL);
    const float var = ts2 * (1.0f / D_MODEL) - mean * mean;
    const float inv = rsqrtf(var + 1e-5f);
    float gg[4], bb[4], o[4];
    ld4(g + threadIdx.x * 4, gg);
    ld4(b + threadIdx.x * 4, bb);
    for (int i = 0; i < 4; ++i) o[i] = (v[i] - mean) * inv * gg[i] + bb[i];
    st4(out + (size_t)row * D_MODEL + threadIdx.x * 4, o);
}

// ---------------- MFMA GEMM: out[M,N] = A[M,K] @ W[N,K]^T (+epilogue) -------
// A, W bf16; 128x128 tile, BK=32, 4 waves (2x2), 4x4 mfma_16x16x32 per wave.
// EPI: 0=none, 1=bias+softplus, 2=bias+gelu, 3=+res, 4=bias+res
template <int EPI, typename RT, typename OT>
__launch_bounds__(256)
__global__ void mfma_gemm(const bf16_t* __restrict__ A, int lda,
                          const bf16_t* __restrict__ W, int ldw,
                          const float* __restrict__ bias,
                          const RT* __restrict__ res,
                          OT* __restrict__ out, int ldo, int nstore,
                          int K) {
    __shared__ bf16_t As[128 * 32];  // [row][k] row-major, 8KB
    __shared__ bf16_t Ws[128 * 32];
    const int tid = threadIdx.x;
    const int lane = tid & 63;
    const int wv = tid >> 6;
    const int wm = (wv & 1) * 64;
    const int wn = (wv >> 1) * 64;
    const int fr = lane & 15;   // fragment row (m or n)
    const int fq = lane >> 4;   // quad: k = fq*8+j ; C/D row = fq*4+r
    const int m0 = blockIdx.y * 128;
    const int n0 = blockIdx.x * 128;

    float4v acc[4][4] = {};

    for (int k0 = 0; k0 < K; k0 += 32) {
#pragma unroll
        for (int q = 0; q < 2; ++q) {
            const int e = q * 256 + tid;  // 0..511 ; row=e>>2, seg=e&3
            gload_lds16(A + (size_t)(m0 + (e >> 2)) * lda + k0 + (e & 3) * 8, &As[e * 8]);
        }
#pragma unroll
        for (int q = 0; q < 2; ++q) {
            const int e = q * 256 + tid;
            gload_lds16(W + (size_t)(n0 + (e >> 2)) * ldw + k0 + (e & 3) * 8, &Ws[e * 8]);
        }
        __syncthreads();  // drains global_load_lds (vmcnt) + makes LDS visible
        short8v a[4], b[4];
#pragma unroll
        for (int i = 0; i < 4; ++i)
            a[i] = *(const short8v*)&As[(wm + i * 16 + fr) * 32 + fq * 8];
#pragma unroll
        for (int j = 0; j < 4; ++j)
            b[j] = *(const short8v*)&Ws[(wn + j * 16 + fr) * 32 + fq * 8];
#pragma unroll
        for (int i = 0; i < 4; ++i)
#pragma unroll
            for (int j = 0; j < 4; ++j)
                acc[i][j] = __builtin_amdgcn_mfma_f32_16x16x32_bf16(a[i], b[j], acc[i][j], 0, 0, 0);
        __syncthreads();  // protect LDS from next iteration's staging
    }

    // epilogue: C/D mapping col=lane&15, row=(lane>>4)*4+reg  [m89-verified]
#pragma unroll
    for (int i = 0; i < 4; ++i) {
#pragma unroll
        for (int j = 0; j < 4; ++j) {
            const int col = n0 + wn + j * 16 + fr;
            if (col < nstore) {
#pragma unroll
                for (int r = 0; r < 4; ++r) {
                    const int row = m0 + wm + i * 16 + fq * 4 + r;
                    float v = acc[i][j][r];
                    if (EPI == 1 || EPI == 2 || EPI == 4) v += bias[col];
                    if (EPI == 1) v = softplusf_(v);
                    if (EPI == 2) v = geluf_(v);
                    if (EPI == 3 || EPI == 4) v += ld1(res + (size_t)row * ldo + col);
                    st1(out + (size_t)row * ldo + col, v);
                }
            }
        }
    }
}

// ---------------- causal depthwise conv (k=4) + SiLU ----------------
__launch_bounds__(256)
__global__ void conv_silu_kernel(const bf16_t* __restrict__ xm, const float* __restrict__ cw,
                                 const float* __restrict__ cb, bf16_t* __restrict__ xa) {
    const int idx = blockIdx.x * 256 + threadIdx.x;  // over NTOK * D_INNER
    const int d = idx & (D_INNER - 1);
    const int bt = idx >> 11;
    const int t = bt & (LL - 1);
    const int b = bt >> 11;
    float acc = cb[d];
#pragma unroll
    for (int k = 0; k < D_CONVK; ++k) {
        const int tt = t - 3 + k;
        if (tt >= 0) {
            acc += b2f(xm[((size_t)(b * LL + tt)) * D_INNER + d]) * cw[d * D_CONVK + k];
        }
    }
    xa[(size_t)idx] = f2b(siluf_(acc));
}

// ---------------- selective scan v3: chunked double-buffered prefetch -------
// thread = (channel c 0..15) x (state n 0..15); 512 blocks.
// dy holds delta on input; y is written over it (same addresses, read-then-write
// within the lockstep wave => safe). Loads of chunk c+1 precede stores of chunk
// c in program order => one-chunk prefetch by construction.
#define TCH 8
__device__ __forceinline__ void scan_load(int t0, const bf16_t* dptr, const bf16_t* uptr,
                                          const bf16_t* bcp, const bf16_t* zptr, int n,
                                          float* dlt, float* u, float* Bv, float* Cv, float* zz) {
#pragma unroll
    for (int i = 0; i < TCH; ++i) {
        const size_t t = (size_t)(t0 + i);
        dlt[i] = b2f(dptr[t * D_INNER]);
        u[i]   = b2f(uptr[t * D_INNER]);
        Bv[i]  = b2f(bcp[t * 96 + DT_RANK + n]);
        Cv[i]  = b2f(bcp[t * 96 + DT_RANK + D_STATE + n]);
        zz[i]  = b2f(zptr[t * D_INNER]);
    }
}

__launch_bounds__(256)
__global__ void scan_kernel(bf16_t* dy,                       // delta in / y out (aliased!)
                            const bf16_t* __restrict__ xa,
                            const bf16_t* __restrict__ xdbl,
                            const bf16_t* __restrict__ z,
                            const float* __restrict__ A_log,
                            const float* __restrict__ Dp) {
    const int b = blockIdx.x >> 7;            // 4 b x 128 d-tiles
    const int d0 = (blockIdx.x & 127) << 4;
    const int c = threadIdx.x >> 4;
    const int n = threadIdx.x & 15;
    const int d = d0 + c;
    const float Acoef = -expf(A_log[d * D_STATE + n]);
    const float Dd = Dp[d];
    float h = 0.f;
    bf16_t* dptr = dy + (size_t)b * LL * D_INNER + d;
    const bf16_t* uptr = xa + (size_t)b * LL * D_INNER + d;
    const bf16_t* bcp = xdbl + (size_t)b * LL * 96;
    const bf16_t* zptr = z + (size_t)b * LL * D_INNER + d;

    float dA_[TCH], uA_[TCH], BA_[TCH], CA_[TCH], zA_[TCH];
    float dB_[TCH], uB_[TCH], BB_[TCH], CB_[TCH], zB_[TCH];

    scan_load(0, dptr, uptr, bcp, zptr, n, dA_, uA_, BA_, CA_, zA_);

    const int NCH = LL / TCH;  // 256
    for (int ch = 0; ch < NCH; ch += 2) {
        // prefetch chunk ch+1 (always exists: NCH even)
        scan_load((ch + 1) * TCH, dptr, uptr, bcp, zptr, n, dB_, uB_, BB_, CB_, zB_);
        // compute chunk ch
#pragma unroll
        for (int i = 0; i < TCH; ++i) {
            const int t = ch * TCH + i;
            const float dA = __expf(dA_[i] * Acoef);
            h = h * dA + dA_[i] * uA_[i] * BA_[i];
            float yv = h * CA_[i];
            yv += __shfl_xor(yv, 1);
            yv += __shfl_xor(yv, 2);
            yv += __shfl_xor(yv, 4);
            yv += __shfl_xor(yv, 8);
            if (n == 0)
                dptr[(size_t)t * D_INNER] = f2b((yv + uA_[i] * Dd) * siluf_(zA_[i]));
        }
        // prefetch chunk ch+2
        if (ch + 2 < NCH)
            scan_load((ch + 2) * TCH, dptr, uptr, bcp, zptr, n, dA_, uA_, BA_, CA_, zA_);
        // compute chunk ch+1
#pragma unroll
        for (int i = 0; i < TCH; ++i) {
            const int t = (ch + 1) * TCH + i;
            const float dA = __expf(dB_[i] * Acoef);
            h = h * dA + dB_[i] * uB_[i] * BB_[i];
            float yv = h * CB_[i];
            yv += __shfl_xor(yv, 1);
            yv += __shfl_xor(yv, 2);
            yv += __shfl_xor(yv, 4);
            yv += __shfl_xor(yv, 8);
            if (n == 0)
                dptr[(size_t)t * D_INNER] = f2b((yv + uB_[i] * Dd) * siluf_(zB_[i]));
        }
    }
}

// ---------------- launch ----------------
extern "C" void kernel_launch(void* const* d_in, const int* in_sizes, int n_in,
                              void* d_out, int out_size, void* d_ws, size_t ws_size,
                              hipStream_t stream) {
    const float* x         = (const float*)d_in[0];
    const float* ln1_g     = (const float*)d_in[1];
    const float* ln1_b     = (const float*)d_in[2];
    const float* in_proj_w = (const float*)d_in[3];
    const float* conv_w    = (const float*)d_in[4];
    const float* conv_b    = (const float*)d_in[5];
    const float* x_proj_w  = (const float*)d_in[6];
    const float* dt_proj_w = (const float*)d_in[7];
    const float* dt_proj_b = (const float*)d_in[8];
    const float* A_log     = (const float*)d_in[9];
    const float* Dp        = (const float*)d_in[10];
    const float* out_proj_w= (const float*)d_in[11];
    const float* ln2_g     = (const float*)d_in[12];
    const float* ln2_b     = (const float*)d_in[13];
    const float* mlp_w1    = (const float*)d_in[14];
    const float* mlp_b1    = (const float*)d_in[15];
    const float* mlp_w2    = (const float*)d_in[16];
    const float* mlp_b2    = (const float*)d_in[17];
    float* outp = (float*)d_out;

    // workspace layout (bf16 elems); total 78,774,272 elems = 157.5 MB
    bf16_t* ws    = (bf16_t*)d_ws;
    bf16_t* h     = ws;               //  8,388,608  (NTOK x 1024)  later: h2
    bf16_t* xm    = ws + 8388608;     // 16,777,216  (NTOK x 2048)  later: delta, then y
    bf16_t* z     = ws + 25165824;    // 16,777,216  (NTOK x 2048)  later: m1
    bf16_t* xa    = ws + 41943040;    // 16,777,216  (NTOK x 2048)
    bf16_t* xdbl  = ws + 58720256;    //    786,432  (NTOK x 96)
    bf16_t* xres  = ws + 59506688;    //  8,388,608  (NTOK x 1024)
    bf16_t* wb_in = ws + 67895296;    //  4,194,304  (4096 x 1024)
    bf16_t* wb_out= ws + 72089600;    //  2,097,152  (1024 x 2048)
    bf16_t* wb_m1 = ws + 74186752;    //  2,097,152  (2048 x 1024)
    bf16_t* wb_m2 = ws + 76283904;    //  2,097,152  (1024 x 2048)
    bf16_t* wb_dt = ws + 78381056;    //    131,072  (2048 x 64)
    bf16_t* wb_xp = ws + 78512128;    //    262,144  (128 x 2048, padded)
    bf16_t* delta = xm;
    bf16_t* y     = xm;
    bf16_t* h2    = h;
    bf16_t* m1    = z;

    // 0. weight conversions fp32 -> bf16
    wconv_kernel<<<4194304 / 1024, 256, 0, stream>>>(in_proj_w, wb_in, 4194304);
    wconv_kernel<<<2097152 / 1024, 256, 0, stream>>>(out_proj_w, wb_out, 2097152);
    wconv_kernel<<<2097152 / 1024, 256, 0, stream>>>(mlp_w1, wb_m1, 2097152);
    wconv_kernel<<<2097152 / 1024, 256, 0, stream>>>(mlp_w2, wb_m2, 2097152);
    wconv_kernel<<<131072 / 1024, 256, 0, stream>>>(dt_proj_w, wb_dt, 131072);
    xproj_pad_kernel<<<262144 / 1024, 256, 0, stream>>>(x_proj_w, wb_xp);

    // 1. LN1 (fp32 in)
    ln_kernel<float><<<NTOK, 256, 0, stream>>>(x, ln1_g, ln1_b, h);
    // 2a. in_proj (x half): xm = h @ W[0:2048].T   M=8192 N=2048 K=1024
    mfma_gemm<0, float, bf16_t><<<dim3(16, 64), 256, 0, stream>>>(
        h, D_MODEL, wb_in, D_MODEL, nullptr, (const float*)nullptr, xm, 2048, 2048, D_MODEL);
    // 2b. in_proj (z half)
    mfma_gemm<0, float, bf16_t><<<dim3(16, 64), 256, 0, stream>>>(
        h, D_MODEL, wb_in + (size_t)D_INNER * D_MODEL, D_MODEL, nullptr,
        (const float*)nullptr, z, 2048, 2048, D_MODEL);
    // 3. conv + silu -> xa
    conv_silu_kernel<<<(NTOK * D_INNER) / 256, 256, 0, stream>>>(xm, conv_w, conv_b, xa);
    // 4. x_proj: xdbl = xa @ x_proj_w.T   N=128(pad) store 96, K=2048
    mfma_gemm<0, float, bf16_t><<<dim3(1, 64), 256, 0, stream>>>(
        xa, D_INNER, wb_xp, D_INNER, nullptr, (const float*)nullptr, xdbl, 96, 96, D_INNER);
    // 5. dt_proj + softplus: delta = softplus(xdbl[:, :64] @ dt.T + b)  K=64
    mfma_gemm<1, float, bf16_t><<<dim3(16, 64), 256, 0, stream>>>(
        xdbl, 96, wb_dt, DT_RANK, dt_proj_b, (const float*)nullptr, delta, 2048, 2048, DT_RANK);
    // 6. selective scan (+ u*D, * silu(z)) -> y (over delta buffer)
    scan_kernel<<<BB * (D_INNER / 16), 256, 0, stream>>>(delta, xa, xdbl, z, A_log, Dp);
    // 7. out_proj + residual x (fp32) -> xres   N=1024 K=2048
    mfma_gemm<3, float, bf16_t><<<dim3(8, 64), 256, 0, stream>>>(
        y, D_INNER, wb_out, D_INNER, nullptr, x, xres, D_MODEL, D_MODEL, D_INNER);
    // 8. LN2 (bf16 in)
    ln_kernel<bf16_t><<<NTOK, 256, 0, stream>>>(xres, ln2_g, ln2_b, h2);
    // 9. mlp1 + gelu   N=2048 K=1024
    mfma_gemm<2, float, bf16_t><<<dim3(16, 64), 256, 0, stream>>>(
        h2, D_MODEL, wb_m1, D_MODEL, mlp_b1, (const float*)nullptr, m1, 2048, 2048, D_MODEL);
    // 10. mlp2 + bias + residual xres -> out (fp32)   N=1024 K=2048
    mfma_gemm<4, bf16_t, float><<<dim3(8, 64), 256, 0, stream>>>(
        m1, MLP_HID, wb_m2, MLP_HID, mlp_b2, xres, outp, D_MODEL, D_MODEL, MLP_HID);
}

// Round 5
// 975.437 us; speedup vs baseline: 4.4376x; 1.6481x over previous
//
#include <hip/hip_runtime.h>
#include <math.h>

// Problem constants
#define D_MODEL 1024
#define D_STATE 16
#define D_CONVK 4
#define D_INNER 2048
#define DT_RANK 64
#define MLP_HID 2048
#define BB 4
#define LL 2048
#define NTOK (BB * LL)  // 8192
#define TSEG 128
#define NSEG 16

typedef unsigned short bf16_t;
typedef __attribute__((ext_vector_type(8))) short short8v;          // 8 bf16 (4 VGPRs)
typedef __attribute__((ext_vector_type(8))) unsigned short ushort8v;
typedef __attribute__((ext_vector_type(4))) float float4v;          // 4 fp32 acc

// ---------------- dtype helpers ----------------
__device__ __forceinline__ float b2f(bf16_t u) {
    return __uint_as_float(((unsigned int)u) << 16);
}
__device__ __forceinline__ bf16_t f2b(float f) {
    unsigned int x = __float_as_uint(f);
    unsigned int r = (x + 0x7FFFu + ((x >> 16) & 1u)) >> 16;
    return (bf16_t)r;
}
__device__ __forceinline__ void ld4(const float* p, float v[4]) {
    const float4 t = *(const float4*)p;
    v[0] = t.x; v[1] = t.y; v[2] = t.z; v[3] = t.w;
}
__device__ __forceinline__ void ld4(const bf16_t* p, float v[4]) {
    const ushort4 t = *(const ushort4*)p;
    v[0] = b2f(t.x); v[1] = b2f(t.y); v[2] = b2f(t.z); v[3] = b2f(t.w);
}
__device__ __forceinline__ float ld1(const float* p) { return *p; }
__device__ __forceinline__ float ld1(const bf16_t* p) { return b2f(*p); }
__device__ __forceinline__ void st1(float* p, float v) { *p = v; }
__device__ __forceinline__ void st1(bf16_t* p, float v) { *p = f2b(v); }
__device__ __forceinline__ void st4(bf16_t* p, const float v[4]) {
    *(ushort4*)p = make_ushort4(f2b(v[0]), f2b(v[1]), f2b(v[2]), f2b(v[3]));
}
__device__ __forceinline__ void unpack8(ushort8v p, float* f) {
#pragma unroll
    for (int i = 0; i < 8; ++i) f[i] = b2f((bf16_t)p[i]);
}

__device__ __forceinline__ float sigmoidf_(float x) { return 1.0f / (1.0f + __expf(-x)); }
__device__ __forceinline__ float siluf_(float x) { return x * sigmoidf_(x); }
__device__ __forceinline__ float softplusf_(float x) {
    return (x > 20.0f) ? x : log1pf(expf(x));
}
__device__ __forceinline__ float geluf_(float x) {
    return 0.5f * x * (1.0f + erff(x * 0.7071067811865475f));
}

// async global->LDS, 16B per lane (dest = wave-uniform base + lane*16)
__device__ __forceinline__ void gload_lds16(const bf16_t* g, bf16_t* l) {
    __builtin_amdgcn_global_load_lds(
        (__attribute__((address_space(1))) void*)(g),
        (__attribute__((address_space(3))) void*)(l), 16, 0, 0);
}

// ---------------- weight fp32 -> bf16 convert ----------------
__launch_bounds__(256)
__global__ void wconv_kernel(const float* __restrict__ src, bf16_t* __restrict__ dst, int n) {
    const int i = (blockIdx.x * 256 + threadIdx.x) * 4;
    if (i < n) {
        float v[4];
        ld4(src + i, v);
        st4(dst + i, v);
    }
}

// x_proj pad: dst is 128 x 2048 bf16, src is 96 x 2048 fp32, rows 96..127 zero
__launch_bounds__(256)
__global__ void xproj_pad_kernel(const float* __restrict__ src, bf16_t* __restrict__ dst) {
    const int i = (blockIdx.x * 256 + threadIdx.x) * 4;  // over 128*2048
    float v[4] = {0.f, 0.f, 0.f, 0.f};
    if (i < 96 * 2048) ld4(src + i, v);
    st4(dst + i, v);
}

// ---------------- LayerNorm (row = 1024): T in, bf16 out ----------------
template <typename T>
__launch_bounds__(256)
__global__ void ln_kernel(const T* __restrict__ x, const float* __restrict__ g,
                          const float* __restrict__ b, bf16_t* __restrict__ out) {
    const int row = blockIdx.x;
    float v[4];
    ld4(x + (size_t)row * D_MODEL + threadIdx.x * 4, v);
    float s = v[0] + v[1] + v[2] + v[3];
    float s2 = v[0] * v[0] + v[1] * v[1] + v[2] * v[2] + v[3] * v[3];
    for (int off = 32; off > 0; off >>= 1) {
        s += __shfl_down(s, off);
        s2 += __shfl_down(s2, off);
    }
    __shared__ float ls[4], ls2[4];
    const int wid = threadIdx.x >> 6;
    if ((threadIdx.x & 63) == 0) { ls[wid] = s; ls2[wid] = s2; }
    __syncthreads();
    const float ts = ls[0] + ls[1] + ls[2] + ls[3];
    const float ts2 = ls2[0] + ls2[1] + ls2[2] + ls2[3];
    const float mean = ts * (1.0f / D_MODEL);
    const float var = ts2 * (1.0f / D_MODEL) - mean * mean;
    const float inv = rsqrtf(var + 1e-5f);
    float gg[4], bb[4], o[4];
    ld4(g + threadIdx.x * 4, gg);
    ld4(b + threadIdx.x * 4, bb);
    for (int i = 0; i < 4; ++i) o[i] = (v[i] - mean) * inv * gg[i] + bb[i];
    st4(out + (size_t)row * D_MODEL + threadIdx.x * 4, o);
}

// ---------------- MFMA GEMM: out[M,N] = A[M,K] @ W[N,K]^T (+epilogue) -------
// A, W bf16; 128x128 tile, BK=32, 4 waves (2x2), 4x4 mfma_16x16x32 per wave.
// EPI: 0=none, 1=bias+softplus, 2=bias+gelu, 3=+res, 4=bias+res
template <int EPI, typename RT, typename OT>
__launch_bounds__(256)
__global__ void mfma_gemm(const bf16_t* __restrict__ A, int lda,
                          const bf16_t* __restrict__ W, int ldw,
                          const float* __restrict__ bias,
                          const RT* __restrict__ res, int ldr,
                          OT* __restrict__ out, int ldo, int nstore,
                          int K) {
    __shared__ bf16_t As[128 * 32];  // [row][k] row-major, 8KB
    __shared__ bf16_t Ws[128 * 32];
    const int tid = threadIdx.x;
    const int lane = tid & 63;
    const int wv = tid >> 6;
    const int wm = (wv & 1) * 64;
    const int wn = (wv >> 1) * 64;
    const int fr = lane & 15;   // fragment row (m or n)
    const int fq = lane >> 4;   // quad: k = fq*8+j ; C/D row = fq*4+r
    const int m0 = blockIdx.y * 128;
    const int n0 = blockIdx.x * 128;

    float4v acc[4][4] = {};

    for (int k0 = 0; k0 < K; k0 += 32) {
#pragma unroll
        for (int q = 0; q < 2; ++q) {
            const int e = q * 256 + tid;  // 0..511 ; row=e>>2, seg=e&3
            gload_lds16(A + (size_t)(m0 + (e >> 2)) * lda + k0 + (e & 3) * 8, &As[e * 8]);
        }
#pragma unroll
        for (int q = 0; q < 2; ++q) {
            const int e = q * 256 + tid;
            gload_lds16(W + (size_t)(n0 + (e >> 2)) * ldw + k0 + (e & 3) * 8, &Ws[e * 8]);
        }
        __syncthreads();  // drains global_load_lds (vmcnt) + makes LDS visible
        short8v a[4], b[4];
#pragma unroll
        for (int i = 0; i < 4; ++i)
            a[i] = *(const short8v*)&As[(wm + i * 16 + fr) * 32 + fq * 8];
#pragma unroll
        for (int j = 0; j < 4; ++j)
            b[j] = *(const short8v*)&Ws[(wn + j * 16 + fr) * 32 + fq * 8];
#pragma unroll
        for (int i = 0; i < 4; ++i)
#pragma unroll
            for (int j = 0; j < 4; ++j)
                acc[i][j] = __builtin_amdgcn_mfma_f32_16x16x32_bf16(a[i], b[j], acc[i][j], 0, 0, 0);
        __syncthreads();  // protect LDS from next iteration's staging
    }

    // epilogue: C/D mapping col=lane&15, row=(lane>>4)*4+reg  [m89-verified]
#pragma unroll
    for (int i = 0; i < 4; ++i) {
#pragma unroll
        for (int j = 0; j < 4; ++j) {
            const int col = n0 + wn + j * 16 + fr;
            if (col < nstore) {
#pragma unroll
                for (int r = 0; r < 4; ++r) {
                    const int row = m0 + wm + i * 16 + fq * 4 + r;
                    float v = acc[i][j][r];
                    if (EPI == 1 || EPI == 2 || EPI == 4) v += bias[col];
                    if (EPI == 1) v = softplusf_(v);
                    if (EPI == 2) v = geluf_(v);
                    if (EPI == 3 || EPI == 4) v += ld1(res + (size_t)row * ldr + col);
                    st1(out + (size_t)row * ldo + col, v);
                }
            }
        }
    }
}

// ---------------- causal depthwise conv (k=4) + SiLU ----------------
// xm lives in xz cols 0..2047 (ld 4096)
__launch_bounds__(256)
__global__ void conv_silu_kernel(const bf16_t* __restrict__ xm, const float* __restrict__ cw,
                                 const float* __restrict__ cb, bf16_t* __restrict__ xa) {
    const int idx = blockIdx.x * 256 + threadIdx.x;  // over NTOK * D_INNER
    const int d = idx & (D_INNER - 1);
    const int bt = idx >> 11;
    const int t = bt & (LL - 1);
    const int b = bt >> 11;
    float acc = cb[d];
#pragma unroll
    for (int k = 0; k < D_CONVK; ++k) {
        const int tt = t - 3 + k;
        if (tt >= 0) {
            acc += b2f(xm[((size_t)(b * LL + tt)) * 4096 + d]) * cw[d * D_CONVK + k];
        }
    }
    xa[(size_t)idx] = f2b(siluf_(acc));
}

// ---------------- selective scan: segmented two-pass, 16 states/thread ------
// Pass 1: per (b, segment s, channel d): scan segment from h=0, record
//         P[n] = prod dA and partial h. Pass combine: stitch over s.
//         Pass 2: replay with correct h_init, emit y = (sum h*C + u*D)*silu(z).
// delta lives in xz cols 0..2047 (ld 4096); z in cols 2048..4095; y overwrites
// delta in-thread (packet loads precede stores in program order).

__launch_bounds__(256)
__global__ void scan_pass1(const bf16_t* __restrict__ delta,  // ld 4096
                           const bf16_t* __restrict__ xa,     // ld 2048
                           const bf16_t* __restrict__ xdbl,   // ld 96
                           const float* __restrict__ A_log,
                           float* __restrict__ Pbuf, float* __restrict__ Hbuf) {
    const int bs = blockIdx.x;  // b*NSEG + s
    const int b = bs >> 4, s = bs & 15;
    const int d = blockIdx.y * 256 + threadIdx.x;
    float Ac[16], h[16], P[16];
#pragma unroll
    for (int n = 0; n < 16; ++n) {
        Ac[n] = -__expf(A_log[d * 16 + n]);
        h[n] = 0.f;
        P[n] = 1.f;
    }
    const size_t tokbase = (size_t)b * LL + s * TSEG;
    float dlt, u;
    ushort8v B0, B1;
    {
        const size_t tok = tokbase;
        dlt = b2f(delta[tok * 4096 + d]);
        u = b2f(xa[tok * 2048 + d]);
        B0 = *(const ushort8v*)&xdbl[tok * 96 + 64];
        B1 = *(const ushort8v*)&xdbl[tok * 96 + 72];
    }
    for (int t = 0; t < TSEG; ++t) {
        const int tn = (t + 1 < TSEG) ? t + 1 : t;
        const size_t tok = tokbase + tn;
        const float dltn = b2f(delta[tok * 4096 + d]);
        const float un = b2f(xa[tok * 2048 + d]);
        const ushort8v B0n = *(const ushort8v*)&xdbl[tok * 96 + 64];
        const ushort8v B1n = *(const ushort8v*)&xdbl[tok * 96 + 72];
        float Bv[16];
        unpack8(B0, Bv);
        unpack8(B1, Bv + 8);
        const float s0 = dlt * u;
#pragma unroll
        for (int n = 0; n < 16; ++n) {
            const float dA = __expf(dlt * Ac[n]);
            P[n] *= dA;
            h[n] = h[n] * dA + s0 * Bv[n];
        }
        dlt = dltn; u = un; B0 = B0n; B1 = B1n;
    }
    const size_t ob = ((((size_t)b * NSEG + s) * 2048) + d) * 16;
#pragma unroll
    for (int q = 0; q < 4; ++q) {
        *(float4*)(Pbuf + ob + q * 4) = make_float4(P[q*4], P[q*4+1], P[q*4+2], P[q*4+3]);
        *(float4*)(Hbuf + ob + q * 4) = make_float4(h[q*4], h[q*4+1], h[q*4+2], h[q*4+3]);
    }
}

__launch_bounds__(256)
__global__ void scan_combine(const float* __restrict__ Pbuf, float* __restrict__ Hbuf) {
    const int tid = blockIdx.x * 256 + threadIdx.x;  // 131072 = 4b * 2048d * 16n
    const int n = tid & 15;
    const int d = (tid >> 4) & 2047;
    const int b = tid >> 15;
    float carry = 0.f;
    for (int s = 0; s < NSEG; ++s) {
        const size_t idx = ((((size_t)b * NSEG + s) * 2048) + d) * 16 + n;
        const float P = Pbuf[idx];
        const float Hp = Hbuf[idx];
        Hbuf[idx] = carry;            // h_init for segment s
        carry = Hp + P * carry;
    }
}

__launch_bounds__(256)
__global__ void scan_pass2(bf16_t* xz,                        // delta in / y out + z
                           const bf16_t* __restrict__ xa,
                           const bf16_t* __restrict__ xdbl,
                           const float* __restrict__ A_log,
                           const float* __restrict__ Dp,
                           const float* __restrict__ Hbuf) {
    const int bs = blockIdx.x;
    const int b = bs >> 4, s = bs & 15;
    const int d = blockIdx.y * 256 + threadIdx.x;
    float Ac[16], h[16];
    const size_t hb = ((((size_t)b * NSEG + s) * 2048) + d) * 16;
#pragma unroll
    for (int n = 0; n < 16; ++n) {
        Ac[n] = -__expf(A_log[d * 16 + n]);
        h[n] = Hbuf[hb + n];
    }
    const float Dd = Dp[d];
    const size_t tokbase = (size_t)b * LL + s * TSEG;
    float dlt, u, zz;
    ushort8v B0, B1, C0, C1;
    {
        const size_t tok = tokbase;
        dlt = b2f(xz[tok * 4096 + d]);
        u = b2f(xa[tok * 2048 + d]);
        zz = b2f(xz[tok * 4096 + 2048 + d]);
        B0 = *(const ushort8v*)&xdbl[tok * 96 + 64];
        B1 = *(const ushort8v*)&xdbl[tok * 96 + 72];
        C0 = *(const ushort8v*)&xdbl[tok * 96 + 80];
        C1 = *(const ushort8v*)&xdbl[tok * 96 + 88];
    }
    for (int t = 0; t < TSEG; ++t) {
        const int tn = (t + 1 < TSEG) ? t + 1 : t;
        const size_t tok = tokbase + tn;
        const float dltn = b2f(xz[tok * 4096 + d]);
        const float un = b2f(xa[tok * 2048 + d]);
        const float zzn = b2f(xz[tok * 4096 + 2048 + d]);
        const ushort8v B0n = *(const ushort8v*)&xdbl[tok * 96 + 64];
        const ushort8v B1n = *(const ushort8v*)&xdbl[tok * 96 + 72];
        const ushort8v C0n = *(const ushort8v*)&xdbl[tok * 96 + 80];
        const ushort8v C1n = *(const ushort8v*)&xdbl[tok * 96 + 88];
        float Bv[16], Cv[16];
        unpack8(B0, Bv); unpack8(B1, Bv + 8);
        unpack8(C0, Cv); unpack8(C1, Cv + 8);
        const float s0 = dlt * u;
        float y = 0.f;
#pragma unroll
        for (int n = 0; n < 16; ++n) {
            const float dA = __expf(dlt * Ac[n]);
            h[n] = h[n] * dA + s0 * Bv[n];
            y = fmaf(h[n], Cv[n], y);
        }
        y = (y + u * Dd) * siluf_(zz);
        xz[(tokbase + t) * 4096 + d] = f2b(y);  // after next-packet loads
        dlt = dltn; u = un; zz = zzn;
        B0 = B0n; B1 = B1n; C0 = C0n; C1 = C1n;
    }
}

// ---------------- launch ----------------
extern "C" void kernel_launch(void* const* d_in, const int* in_sizes, int n_in,
                              void* d_out, int out_size, void* d_ws, size_t ws_size,
                              hipStream_t stream) {
    const float* x         = (const float*)d_in[0];
    const float* ln1_g     = (const float*)d_in[1];
    const float* ln1_b     = (const float*)d_in[2];
    const float* in_proj_w = (const float*)d_in[3];
    const float* conv_w    = (const float*)d_in[4];
    const float* conv_b    = (const float*)d_in[5];
    const float* x_proj_w  = (const float*)d_in[6];
    const float* dt_proj_w = (const float*)d_in[7];
    const float* dt_proj_b = (const float*)d_in[8];
    const float* A_log     = (const float*)d_in[9];
    const float* Dp        = (const float*)d_in[10];
    const float* out_proj_w= (const float*)d_in[11];
    const float* ln2_g     = (const float*)d_in[12];
    const float* ln2_b     = (const float*)d_in[13];
    const float* mlp_w1    = (const float*)d_in[14];
    const float* mlp_b1    = (const float*)d_in[15];
    const float* mlp_w2    = (const float*)d_in[16];
    const float* mlp_b2    = (const float*)d_in[17];
    float* outp = (float*)d_out;

    // workspace layout (bf16 elems); total 78,774,272 elems = 157.5 MB (proven)
    bf16_t* ws    = (bf16_t*)d_ws;
    bf16_t* h     = ws;               //  8,388,608  (NTOK x 1024)  later: h2
    bf16_t* xz    = ws + 8388608;     // 33,554,432  (NTOK x 4096) xm|z; then delta|z; y; m1
    bf16_t* xa    = ws + 41943040;    // 16,777,216  (NTOK x 2048)
    bf16_t* xdbl  = ws + 58720256;    //    786,432  (NTOK x 96)
    bf16_t* xres  = ws + 59506688;    //  8,388,608  (NTOK x 1024) [P/H alias during scan]
    bf16_t* wb_in = ws + 67895296;    //  4,194,304  (4096 x 1024)
    bf16_t* wb_out= ws + 72089600;    //  2,097,152  (1024 x 2048)
    bf16_t* wb_m1 = ws + 74186752;    //  2,097,152  (2048 x 1024)
    bf16_t* wb_m2 = ws + 76283904;    //  2,097,152  (1024 x 2048)
    bf16_t* wb_dt = ws + 78381056;    //    131,072  (2048 x 64)
    bf16_t* wb_xp = ws + 78512128;    //    262,144  (128 x 2048, padded)
    bf16_t* h2    = h;
    bf16_t* delta = xz;               // cols 0..2047, ld 4096 (after conv)
    bf16_t* y     = xz;               // same cols, overwritten by pass2
    bf16_t* m1    = xz;               // same cols, after out_proj
    float*  Pbuf  = (float*)xres;     // 2,097,152 floats
    float*  Hbuf  = Pbuf + 2097152;   // 2,097,152 floats

    // 0. weight conversions fp32 -> bf16
    wconv_kernel<<<4194304 / 1024, 256, 0, stream>>>(in_proj_w, wb_in, 4194304);
    wconv_kernel<<<2097152 / 1024, 256, 0, stream>>>(out_proj_w, wb_out, 2097152);
    wconv_kernel<<<2097152 / 1024, 256, 0, stream>>>(mlp_w1, wb_m1, 2097152);
    wconv_kernel<<<2097152 / 1024, 256, 0, stream>>>(mlp_w2, wb_m2, 2097152);
    wconv_kernel<<<131072 / 1024, 256, 0, stream>>>(dt_proj_w, wb_dt, 131072);
    xproj_pad_kernel<<<262144 / 1024, 256, 0, stream>>>(x_proj_w, wb_xp);

    // 1. LN1 (fp32 in)
    ln_kernel<float><<<NTOK, 256, 0, stream>>>(x, ln1_g, ln1_b, h);
    // 2. in_proj merged: xz = h @ W[0:4096].T   M=8192 N=4096 K=1024
    mfma_gemm<0, float, bf16_t><<<dim3(32, 64), 256, 0, stream>>>(
        h, D_MODEL, wb_in, D_MODEL, nullptr, (const float*)nullptr, 0, xz, 4096, 4096, D_MODEL);
    // 3. conv + silu: xm (xz cols 0..2047) -> xa
    conv_silu_kernel<<<(NTOK * D_INNER) / 256, 256, 0, stream>>>(xz, conv_w, conv_b, xa);
    // 4. x_proj: xdbl = xa @ x_proj_w.T   N=128(pad) store 96, K=2048
    mfma_gemm<0, float, bf16_t><<<dim3(1, 64), 256, 0, stream>>>(
        xa, D_INNER, wb_xp, D_INNER, nullptr, (const float*)nullptr, 0, xdbl, 96, 96, D_INNER);
    // 5. dt_proj + softplus: delta (xz cols 0..2047, xm now dead) K=64
    mfma_gemm<1, float, bf16_t><<<dim3(16, 64), 256, 0, stream>>>(
        xdbl, 96, wb_dt, DT_RANK, dt_proj_b, (const float*)nullptr, 0, delta, 4096, 2048, DT_RANK);
    // 6. selective scan: pass1 / combine / pass2 (y over delta cols)
    scan_pass1<<<dim3(BB * NSEG, D_INNER / 256), 256, 0, stream>>>(
        delta, xa, xdbl, A_log, Pbuf, Hbuf);
    scan_combine<<<(BB * D_INNER * D_STATE) / 256, 256, 0, stream>>>(Pbuf, Hbuf);
    scan_pass2<<<dim3(BB * NSEG, D_INNER / 256), 256, 0, stream>>>(
        xz, xa, xdbl, A_log, Dp, Hbuf);
    // 7. out_proj + residual x (fp32) -> xres   N=1024 K=2048
    mfma_gemm<3, float, bf16_t><<<dim3(8, 64), 256, 0, stream>>>(
        y, 4096, wb_out, D_INNER, nullptr, x, D_MODEL, xres, D_MODEL, D_MODEL, D_INNER);
    // 8. LN2 (bf16 in)
    ln_kernel<bf16_t><<<NTOK, 256, 0, stream>>>(xres, ln2_g, ln2_b, h2);
    // 9. mlp1 + gelu -> m1 (xz cols 0..2047, y dead)   N=2048 K=1024
    mfma_gemm<2, float, bf16_t><<<dim3(16, 64), 256, 0, stream>>>(
        h2, D_MODEL, wb_m1, D_MODEL, mlp_b1, (const float*)nullptr, 0, m1, 4096, 2048, D_MODEL);
    // 10. mlp2 + bias + residual xres -> out (fp32)   N=1024 K=2048
    mfma_gemm<4, bf16_t, float><<<dim3(8, 64), 256, 0, stream>>>(
        m1, 4096, wb_m2, MLP_HID, mlp_b2, xres, D_MODEL, outp, D_MODEL, D_MODEL, MLP_HID);
}

// Round 6
// 740.690 us; speedup vs baseline: 5.8440x; 1.3169x over previous
//
#include <hip/hip_runtime.h>
#include <math.h>

// Problem constants
#define D_MODEL 1024
#define D_STATE 16
#define D_CONVK 4
#define D_INNER 2048
#define DT_RANK 64
#define MLP_HID 2048
#define BB 4
#define LL 2048
#define NTOK (BB * LL)  // 8192
#define TSEG 128
#define NSEG 16

typedef unsigned short bf16_t;
typedef __attribute__((ext_vector_type(8))) short short8v;          // 8 bf16 (4 VGPRs)
typedef __attribute__((ext_vector_type(8))) unsigned short ushort8v;
typedef __attribute__((ext_vector_type(4))) float float4v;          // 4 fp32 acc

// ---------------- dtype helpers ----------------
__device__ __forceinline__ float b2f(bf16_t u) {
    return __uint_as_float(((unsigned int)u) << 16);
}
__device__ __forceinline__ bf16_t f2b(float f) {
    unsigned int x = __float_as_uint(f);
    unsigned int r = (x + 0x7FFFu + ((x >> 16) & 1u)) >> 16;
    return (bf16_t)r;
}
__device__ __forceinline__ void ld4(const float* p, float v[4]) {
    const float4 t = *(const float4*)p;
    v[0] = t.x; v[1] = t.y; v[2] = t.z; v[3] = t.w;
}
__device__ __forceinline__ void ld4(const bf16_t* p, float v[4]) {
    const ushort4 t = *(const ushort4*)p;
    v[0] = b2f(t.x); v[1] = b2f(t.y); v[2] = b2f(t.z); v[3] = b2f(t.w);
}
__device__ __forceinline__ float ld1(const float* p) { return *p; }
__device__ __forceinline__ float ld1(const bf16_t* p) { return b2f(*p); }
__device__ __forceinline__ void st1(float* p, float v) { *p = v; }
__device__ __forceinline__ void st1(bf16_t* p, float v) { *p = f2b(v); }
__device__ __forceinline__ void st4(bf16_t* p, const float v[4]) {
    *(ushort4*)p = make_ushort4(f2b(v[0]), f2b(v[1]), f2b(v[2]), f2b(v[3]));
}
__device__ __forceinline__ void unpack8(ushort8v p, float* f) {
#pragma unroll
    for (int i = 0; i < 8; ++i) f[i] = b2f((bf16_t)p[i]);
}

__device__ __forceinline__ float sigmoidf_(float x) { return 1.0f / (1.0f + __expf(-x)); }
__device__ __forceinline__ float siluf_(float x) { return x * sigmoidf_(x); }
// fast branch-free softplus: max(x,0) + log(1+exp(-|x|)); v_exp/v_log HW ops
__device__ __forceinline__ float softplusf_(float x) {
    return fmaxf(x, 0.0f) + __logf(1.0f + __expf(-fabsf(x)));
}
// fast GELU (tanh form): 0.5x(1+tanh(0.79788456(x+0.044715x^3)))
__device__ __forceinline__ float geluf_(float x) {
    const float u = 0.7978845608028654f * (x + 0.044715f * x * x * x);
    const float e = __expf(2.0f * u);           // inf-safe: e=inf -> th=1
    const float th = 1.0f - 2.0f / (e + 1.0f);
    return 0.5f * x * (1.0f + th);
}

// async global->LDS, 16B per lane (dest = wave-uniform base + lane*16)
__device__ __forceinline__ void gload_lds16(const bf16_t* g, bf16_t* l) {
    __builtin_amdgcn_global_load_lds(
        (__attribute__((address_space(1))) void*)(g),
        (__attribute__((address_space(3))) void*)(l), 16, 0, 0);
}

// ---------------- weight fp32 -> bf16 convert ----------------
__launch_bounds__(256)
__global__ void wconv_kernel(const float* __restrict__ src, bf16_t* __restrict__ dst, int n) {
    const int i = (blockIdx.x * 256 + threadIdx.x) * 4;
    if (i < n) {
        float v[4];
        ld4(src + i, v);
        st4(dst + i, v);
    }
}

// x_proj pad: dst is 128 x 2048 bf16, src is 96 x 2048 fp32, rows 96..127 zero
__launch_bounds__(256)
__global__ void xproj_pad_kernel(const float* __restrict__ src, bf16_t* __restrict__ dst) {
    const int i = (blockIdx.x * 256 + threadIdx.x) * 4;  // over 128*2048
    float v[4] = {0.f, 0.f, 0.f, 0.f};
    if (i < 96 * 2048) ld4(src + i, v);
    st4(dst + i, v);
}

// ---------------- LayerNorm (row = 1024): T in, bf16 out ----------------
template <typename T>
__launch_bounds__(256)
__global__ void ln_kernel(const T* __restrict__ x, const float* __restrict__ g,
                          const float* __restrict__ b, bf16_t* __restrict__ out) {
    const int row = blockIdx.x;
    float v[4];
    ld4(x + (size_t)row * D_MODEL + threadIdx.x * 4, v);
    float s = v[0] + v[1] + v[2] + v[3];
    float s2 = v[0] * v[0] + v[1] * v[1] + v[2] * v[2] + v[3] * v[3];
    for (int off = 32; off > 0; off >>= 1) {
        s += __shfl_down(s, off);
        s2 += __shfl_down(s2, off);
    }
    __shared__ float ls[4], ls2[4];
    const int wid = threadIdx.x >> 6;
    if ((threadIdx.x & 63) == 0) { ls[wid] = s; ls2[wid] = s2; }
    __syncthreads();
    const float ts = ls[0] + ls[1] + ls[2] + ls[3];
    const float ts2 = ls2[0] + ls2[1] + ls2[2] + ls2[3];
    const float mean = ts * (1.0f / D_MODEL);
    const float var = ts2 * (1.0f / D_MODEL) - mean * mean;
    const float inv = rsqrtf(var + 1e-5f);
    float gg[4], bb[4], o[4];
    ld4(g + threadIdx.x * 4, gg);
    ld4(b + threadIdx.x * 4, bb);
    for (int i = 0; i < 4; ++i) o[i] = (v[i] - mean) * inv * gg[i] + bb[i];
    st4(out + (size_t)row * D_MODEL + threadIdx.x * 4, o);
}

// ---------------- MFMA GEMM: out[M,N] = A[M,K] @ W[N,K]^T (+epilogue) -------
// A, W bf16; 128x128 tile, BK=32, 4 waves (2x2), 4x4 mfma_16x16x32 per wave.
// EPI: 0=none, 1=bias+softplus, 2=bias+gelu, 3=+res, 4=bias+res
template <int EPI, typename RT, typename OT>
__launch_bounds__(256)
__global__ void mfma_gemm(const bf16_t* __restrict__ A, int lda,
                          const bf16_t* __restrict__ W, int ldw,
                          const float* __restrict__ bias,
                          const RT* __restrict__ res, int ldr,
                          OT* __restrict__ out, int ldo, int nstore,
                          int K) {
    __shared__ bf16_t As[128 * 32];  // [row][k] row-major, 8KB
    __shared__ bf16_t Ws[128 * 32];
    const int tid = threadIdx.x;
    const int lane = tid & 63;
    const int wv = tid >> 6;
    const int wm = (wv & 1) * 64;
    const int wn = (wv >> 1) * 64;
    const int fr = lane & 15;   // fragment row (m or n)
    const int fq = lane >> 4;   // quad: k = fq*8+j ; C/D row = fq*4+r
    const int m0 = blockIdx.y * 128;
    const int n0 = blockIdx.x * 128;

    float4v acc[4][4] = {};

    for (int k0 = 0; k0 < K; k0 += 32) {
#pragma unroll
        for (int q = 0; q < 2; ++q) {
            const int e = q * 256 + tid;  // 0..511 ; row=e>>2, seg=e&3
            gload_lds16(A + (size_t)(m0 + (e >> 2)) * lda + k0 + (e & 3) * 8, &As[e * 8]);
        }
#pragma unroll
        for (int q = 0; q < 2; ++q) {
            const int e = q * 256 + tid;
            gload_lds16(W + (size_t)(n0 + (e >> 2)) * ldw + k0 + (e & 3) * 8, &Ws[e * 8]);
        }
        __syncthreads();  // drains global_load_lds (vmcnt) + makes LDS visible
        short8v a[4], b[4];
#pragma unroll
        for (int i = 0; i < 4; ++i)
            a[i] = *(const short8v*)&As[(wm + i * 16 + fr) * 32 + fq * 8];
#pragma unroll
        for (int j = 0; j < 4; ++j)
            b[j] = *(const short8v*)&Ws[(wn + j * 16 + fr) * 32 + fq * 8];
#pragma unroll
        for (int i = 0; i < 4; ++i)
#pragma unroll
            for (int j = 0; j < 4; ++j)
                acc[i][j] = __builtin_amdgcn_mfma_f32_16x16x32_bf16(a[i], b[j], acc[i][j], 0, 0, 0);
        __syncthreads();  // protect LDS from next iteration's staging
    }

    // epilogue: C/D mapping col=lane&15, row=(lane>>4)*4+reg  [m89-verified]
#pragma unroll
    for (int i = 0; i < 4; ++i) {
#pragma unroll
        for (int j = 0; j < 4; ++j) {
            const int col = n0 + wn + j * 16 + fr;
            if (col < nstore) {
#pragma unroll
                for (int r = 0; r < 4; ++r) {
                    const int row = m0 + wm + i * 16 + fq * 4 + r;
                    float v = acc[i][j][r];
                    if (EPI == 1 || EPI == 2 || EPI == 4) v += bias[col];
                    if (EPI == 1) v = softplusf_(v);
                    if (EPI == 2) v = geluf_(v);
                    if (EPI == 3 || EPI == 4) v += ld1(res + (size_t)row * ldr + col);
                    st1(out + (size_t)row * ldo + col, v);
                }
            }
        }
    }
}

// ---------------- causal depthwise conv (k=4) + SiLU ----------------
// xm lives in xz cols 0..2047 (ld 4096)
__launch_bounds__(256)
__global__ void conv_silu_kernel(const bf16_t* __restrict__ xm, const float* __restrict__ cw,
                                 const float* __restrict__ cb, bf16_t* __restrict__ xa) {
    const int idx = blockIdx.x * 256 + threadIdx.x;  // over NTOK * D_INNER
    const int d = idx & (D_INNER - 1);
    const int bt = idx >> 11;
    const int t = bt & (LL - 1);
    const int b = bt >> 11;
    float acc = cb[d];
#pragma unroll
    for (int k = 0; k < D_CONVK; ++k) {
        const int tt = t - 3 + k;
        if (tt >= 0) {
            acc += b2f(xm[((size_t)(b * LL + tt)) * 4096 + d]) * cw[d * D_CONVK + k];
        }
    }
    xa[(size_t)idx] = f2b(siluf_(acc));
}

// ---------------- selective scan: segmented two-pass, 16 states/thread ------
__launch_bounds__(256)
__global__ void scan_pass1(const bf16_t* __restrict__ delta,  // ld 4096
                           const bf16_t* __restrict__ xa,     // ld 2048
                           const bf16_t* __restrict__ xdbl,   // ld 96
                           const float* __restrict__ A_log,
                           float* __restrict__ Pbuf, float* __restrict__ Hbuf) {
    const int bs = blockIdx.x;  // b*NSEG + s
    const int b = bs >> 4, s = bs & 15;
    const int d = blockIdx.y * 256 + threadIdx.x;
    float Ac[16], h[16], P[16];
#pragma unroll
    for (int n = 0; n < 16; ++n) {
        Ac[n] = -__expf(A_log[d * 16 + n]);
        h[n] = 0.f;
        P[n] = 1.f;
    }
    const size_t tokbase = (size_t)b * LL + s * TSEG;
    float dlt, u;
    ushort8v B0, B1;
    {
        const size_t tok = tokbase;
        dlt = b2f(delta[tok * 4096 + d]);
        u = b2f(xa[tok * 2048 + d]);
        B0 = *(const ushort8v*)&xdbl[tok * 96 + 64];
        B1 = *(const ushort8v*)&xdbl[tok * 96 + 72];
    }
    for (int t = 0; t < TSEG; ++t) {
        const int tn = (t + 1 < TSEG) ? t + 1 : t;
        const size_t tok = tokbase + tn;
        const float dltn = b2f(delta[tok * 4096 + d]);
        const float un = b2f(xa[tok * 2048 + d]);
        const ushort8v B0n = *(const ushort8v*)&xdbl[tok * 96 + 64];
        const ushort8v B1n = *(const ushort8v*)&xdbl[tok * 96 + 72];
        float Bv[16];
        unpack8(B0, Bv);
        unpack8(B1, Bv + 8);
        const float s0 = dlt * u;
#pragma unroll
        for (int n = 0; n < 16; ++n) {
            const float dA = __expf(dlt * Ac[n]);
            P[n] *= dA;
            h[n] = h[n] * dA + s0 * Bv[n];
        }
        dlt = dltn; u = un; B0 = B0n; B1 = B1n;
    }
    const size_t ob = ((((size_t)b * NSEG + s) * 2048) + d) * 16;
#pragma unroll
    for (int q = 0; q < 4; ++q) {
        *(float4*)(Pbuf + ob + q * 4) = make_float4(P[q*4], P[q*4+1], P[q*4+2], P[q*4+3]);
        *(float4*)(Hbuf + ob + q * 4) = make_float4(h[q*4], h[q*4+1], h[q*4+2], h[q*4+3]);
    }
}

__launch_bounds__(256)
__global__ void scan_combine(const float* __restrict__ Pbuf, float* __restrict__ Hbuf) {
    const int tid = blockIdx.x * 256 + threadIdx.x;  // 131072 = 4b * 2048d * 16n
    const int n = tid & 15;
    const int d = (tid >> 4) & 2047;
    const int b = tid >> 15;
    float carry = 0.f;
    for (int s = 0; s < NSEG; ++s) {
        const size_t idx = ((((size_t)b * NSEG + s) * 2048) + d) * 16 + n;
        const float P = Pbuf[idx];
        const float Hp = Hbuf[idx];
        Hbuf[idx] = carry;            // h_init for segment s
        carry = Hp + P * carry;
    }
}

__launch_bounds__(256)
__global__ void scan_pass2(bf16_t* xz,                        // delta in / y out + z
                           const bf16_t* __restrict__ xa,
                           const bf16_t* __restrict__ xdbl,
                           const float* __restrict__ A_log,
                           const float* __restrict__ Dp,
                           const float* __restrict__ Hbuf) {
    const int bs = blockIdx.x;
    const int b = bs >> 4, s = bs & 15;
    const int d = blockIdx.y * 256 + threadIdx.x;
    float Ac[16], h[16];
    const size_t hb = ((((size_t)b * NSEG + s) * 2048) + d) * 16;
#pragma unroll
    for (int n = 0; n < 16; ++n) {
        Ac[n] = -__expf(A_log[d * 16 + n]);
        h[n] = Hbuf[hb + n];
    }
    const float Dd = Dp[d];
    const size_t tokbase = (size_t)b * LL + s * TSEG;
    float dlt, u, zz;
    ushort8v B0, B1, C0, C1;
    {
        const size_t tok = tokbase;
        dlt = b2f(xz[tok * 4096 + d]);
        u = b2f(xa[tok * 2048 + d]);
        zz = b2f(xz[tok * 4096 + 2048 + d]);
        B0 = *(const ushort8v*)&xdbl[tok * 96 + 64];
        B1 = *(const ushort8v*)&xdbl[tok * 96 + 72];
        C0 = *(const ushort8v*)&xdbl[tok * 96 + 80];
        C1 = *(const ushort8v*)&xdbl[tok * 96 + 88];
    }
    for (int t = 0; t < TSEG; ++t) {
        const int tn = (t + 1 < TSEG) ? t + 1 : t;
        const size_t tok = tokbase + tn;
        const float dltn = b2f(xz[tok * 4096 + d]);
        const float un = b2f(xa[tok * 2048 + d]);
        const float zzn = b2f(xz[tok * 4096 + 2048 + d]);
        const ushort8v B0n = *(const ushort8v*)&xdbl[tok * 96 + 64];
        const ushort8v B1n = *(const ushort8v*)&xdbl[tok * 96 + 72];
        const ushort8v C0n = *(const ushort8v*)&xdbl[tok * 96 + 80];
        const ushort8v C1n = *(const ushort8v*)&xdbl[tok * 96 + 88];
        float Bv[16], Cv[16];
        unpack8(B0, Bv); unpack8(B1, Bv + 8);
        unpack8(C0, Cv); unpack8(C1, Cv + 8);
        const float s0 = dlt * u;
        float y = 0.f;
#pragma unroll
        for (int n = 0; n < 16; ++n) {
            const float dA = __expf(dlt * Ac[n]);
            h[n] = h[n] * dA + s0 * Bv[n];
            y = fmaf(h[n], Cv[n], y);
        }
        y = (y + u * Dd) * siluf_(zz);
        xz[(tokbase + t) * 4096 + d] = f2b(y);  // after next-packet loads
        dlt = dltn; u = un; zz = zzn;
        B0 = B0n; B1 = B1n; C0 = C0n; C1 = C1n;
    }
}

// ---------------- launch ----------------
extern "C" void kernel_launch(void* const* d_in, const int* in_sizes, int n_in,
                              void* d_out, int out_size, void* d_ws, size_t ws_size,
                              hipStream_t stream) {
    const float* x         = (const float*)d_in[0];
    const float* ln1_g     = (const float*)d_in[1];
    const float* ln1_b     = (const float*)d_in[2];
    const float* in_proj_w = (const float*)d_in[3];
    const float* conv_w    = (const float*)d_in[4];
    const float* conv_b    = (const float*)d_in[5];
    const float* x_proj_w  = (const float*)d_in[6];
    const float* dt_proj_w = (const float*)d_in[7];
    const float* dt_proj_b = (const float*)d_in[8];
    const float* A_log     = (const float*)d_in[9];
    const float* Dp        = (const float*)d_in[10];
    const float* out_proj_w= (const float*)d_in[11];
    const float* ln2_g     = (const float*)d_in[12];
    const float* ln2_b     = (const float*)d_in[13];
    const float* mlp_w1    = (const float*)d_in[14];
    const float* mlp_b1    = (const float*)d_in[15];
    const float* mlp_w2    = (const float*)d_in[16];
    const float* mlp_b2    = (const float*)d_in[17];
    float* outp = (float*)d_out;

    // workspace layout (bf16 elems); total 78,774,272 elems = 157.5 MB (proven)
    bf16_t* ws    = (bf16_t*)d_ws;
    bf16_t* h     = ws;               //  8,388,608  (NTOK x 1024)  later: h2
    bf16_t* xz    = ws + 8388608;     // 33,554,432  (NTOK x 4096) xm|z; then delta|z; y; m1
    bf16_t* xa    = ws + 41943040;    // 16,777,216  (NTOK x 2048)
    bf16_t* xdbl  = ws + 58720256;    //    786,432  (NTOK x 96)
    bf16_t* xres  = ws + 59506688;    //  8,388,608  (NTOK x 1024) [P/H alias during scan]
    bf16_t* wb_in = ws + 67895296;    //  4,194,304  (4096 x 1024)
    bf16_t* wb_out= ws + 72089600;    //  2,097,152  (1024 x 2048)
    bf16_t* wb_m1 = ws + 74186752;    //  2,097,152  (2048 x 1024)
    bf16_t* wb_m2 = ws + 76283904;    //  2,097,152  (1024 x 2048)
    bf16_t* wb_dt = ws + 78381056;    //    131,072  (2048 x 64)
    bf16_t* wb_xp = ws + 78512128;    //    262,144  (128 x 2048, padded)
    bf16_t* h2    = h;
    bf16_t* delta = xz;               // cols 0..2047, ld 4096 (after conv)
    bf16_t* y     = xz;               // same cols, overwritten by pass2
    bf16_t* m1    = xz;               // same cols, after out_proj
    float*  Pbuf  = (float*)xres;     // 2,097,152 floats
    float*  Hbuf  = Pbuf + 2097152;   // 2,097,152 floats

    // 0. weight conversions fp32 -> bf16
    wconv_kernel<<<4194304 / 1024, 256, 0, stream>>>(in_proj_w, wb_in, 4194304);
    wconv_kernel<<<2097152 / 1024, 256, 0, stream>>>(out_proj_w, wb_out, 2097152);
    wconv_kernel<<<2097152 / 1024, 256, 0, stream>>>(mlp_w1, wb_m1, 2097152);
    wconv_kernel<<<2097152 / 1024, 256, 0, stream>>>(mlp_w2, wb_m2, 2097152);
    wconv_kernel<<<131072 / 1024, 256, 0, stream>>>(dt_proj_w, wb_dt, 131072);
    xproj_pad_kernel<<<262144 / 1024, 256, 0, stream>>>(x_proj_w, wb_xp);

    // 1. LN1 (fp32 in)
    ln_kernel<float><<<NTOK, 256, 0, stream>>>(x, ln1_g, ln1_b, h);
    // 2. in_proj merged: xz = h @ W[0:4096].T   M=8192 N=4096 K=1024
    mfma_gemm<0, float, bf16_t><<<dim3(32, 64), 256, 0, stream>>>(
        h, D_MODEL, wb_in, D_MODEL, nullptr, (const float*)nullptr, 0, xz, 4096, 4096, D_MODEL);
    // 3. conv + silu: xm (xz cols 0..2047) -> xa
    conv_silu_kernel<<<(NTOK * D_INNER) / 256, 256, 0, stream>>>(xz, conv_w, conv_b, xa);
    // 4. x_proj: xdbl = xa @ x_proj_w.T   N=128(pad) store 96, K=2048
    mfma_gemm<0, float, bf16_t><<<dim3(1, 64), 256, 0, stream>>>(
        xa, D_INNER, wb_xp, D_INNER, nullptr, (const float*)nullptr, 0, xdbl, 96, 96, D_INNER);
    // 5. dt_proj + softplus: delta (xz cols 0..2047, xm now dead) K=64
    mfma_gemm<1, float, bf16_t><<<dim3(16, 64), 256, 0, stream>>>(
        xdbl, 96, wb_dt, DT_RANK, dt_proj_b, (const float*)nullptr, 0, delta, 4096, 2048, DT_RANK);
    // 6. selective scan: pass1 / combine / pass2 (y over delta cols)
    scan_pass1<<<dim3(BB * NSEG, D_INNER / 256), 256, 0, stream>>>(
        delta, xa, xdbl, A_log, Pbuf, Hbuf);
    scan_combine<<<(BB * D_INNER * D_STATE) / 256, 256, 0, stream>>>(Pbuf, Hbuf);
    scan_pass2<<<dim3(BB * NSEG, D_INNER / 256), 256, 0, stream>>>(
        xz, xa, xdbl, A_log, Dp, Hbuf);
    // 7. out_proj + residual x (fp32) -> xres   N=1024 K=2048
    mfma_gemm<3, float, bf16_t><<<dim3(8, 64), 256, 0, stream>>>(
        y, 4096, wb_out, D_INNER, nullptr, x, D_MODEL, xres, D_MODEL, D_MODEL, D_INNER);
    // 8. LN2 (bf16 in)
    ln_kernel<bf16_t><<<NTOK, 256, 0, stream>>>(xres, ln2_g, ln2_b, h2);
    // 9. mlp1 + gelu -> m1 (xz cols 0..2047, y dead)   N=2048 K=1024
    mfma_gemm<2, float, bf16_t><<<dim3(16, 64), 256, 0, stream>>>(
        h2, D_MODEL, wb_m1, D_MODEL, mlp_b1, (const float*)nullptr, 0, m1, 4096, 2048, D_MODEL);
    // 10. mlp2 + bias + residual xres -> out (fp32)   N=1024 K=2048
    mfma_gemm<4, bf16_t, float><<<dim3(8, 64), 256, 0, stream>>>(
        m1, 4096, wb_m2, MLP_HID, mlp_b2, xres, D_MODEL, outp, D_MODEL, D_MODEL, MLP_HID);
}

// Round 7
// 707.146 us; speedup vs baseline: 6.1212x; 1.0474x over previous
//
#include <hip/hip_runtime.h>
#include <math.h>

// Problem constants
#define D_MODEL 1024
#define D_STATE 16
#define D_CONVK 4
#define D_INNER 2048
#define DT_RANK 64
#define MLP_HID 2048
#define BB 4
#define LL 2048
#define NTOK (BB * LL)  // 8192
#define TSEG 128
#define NSEG 16

typedef unsigned short bf16_t;
typedef __attribute__((ext_vector_type(8))) short short8v;          // 8 bf16 (4 VGPRs)
typedef __attribute__((ext_vector_type(8))) unsigned short ushort8v;
typedef __attribute__((ext_vector_type(4))) float float4v;          // 4 fp32 acc

// workspace offsets (bf16 elems); total 78,774,272 = 157.5 MB (proven cap)
#define WS_H      0u
#define WS_XM     8388608u
#define WS_Z      25165824u
#define WS_XA     41943040u
#define WS_XDBL   58720256u
#define WS_XRES   59506688u
#define WS_WIN    67895296u
#define WS_WOUT   72089600u
#define WS_WM1    74186752u
#define WS_WM2    76283904u
#define WS_WDT    78381056u
#define WS_WXP    78512128u

// ---------------- dtype helpers ----------------
__device__ __forceinline__ float b2f(bf16_t u) {
    return __uint_as_float(((unsigned int)u) << 16);
}
__device__ __forceinline__ bf16_t f2b(float f) {
    unsigned int x = __float_as_uint(f);
    unsigned int r = (x + 0x7FFFu + ((x >> 16) & 1u)) >> 16;
    return (bf16_t)r;
}
__device__ __forceinline__ void ld4(const float* p, float v[4]) {
    const float4 t = *(const float4*)p;
    v[0] = t.x; v[1] = t.y; v[2] = t.z; v[3] = t.w;
}
__device__ __forceinline__ void ld4(const bf16_t* p, float v[4]) {
    const ushort4 t = *(const ushort4*)p;
    v[0] = b2f(t.x); v[1] = b2f(t.y); v[2] = b2f(t.z); v[3] = b2f(t.w);
}
__device__ __forceinline__ float ld1(const float* p) { return *p; }
__device__ __forceinline__ float ld1(const bf16_t* p) { return b2f(*p); }
__device__ __forceinline__ void st1(float* p, float v) { *p = v; }
__device__ __forceinline__ void st1(bf16_t* p, float v) { *p = f2b(v); }
__device__ __forceinline__ void st4(bf16_t* p, const float v[4]) {
    *(ushort4*)p = make_ushort4(f2b(v[0]), f2b(v[1]), f2b(v[2]), f2b(v[3]));
}
__device__ __forceinline__ void unpack8(ushort8v p, float* f) {
#pragma unroll
    for (int i = 0; i < 8; ++i) f[i] = b2f((bf16_t)p[i]);
}

__device__ __forceinline__ float sigmoidf_(float x) { return 1.0f / (1.0f + __expf(-x)); }
__device__ __forceinline__ float siluf_(float x) { return x * sigmoidf_(x); }
// fast branch-free softplus: max(x,0) + log(1+exp(-|x|)); v_exp/v_log HW ops
__device__ __forceinline__ float softplusf_(float x) {
    return fmaxf(x, 0.0f) + __logf(1.0f + __expf(-fabsf(x)));
}
// fast GELU (tanh form)
__device__ __forceinline__ float geluf_(float x) {
    const float u = 0.7978845608028654f * (x + 0.044715f * x * x * x);
    const float e = __expf(2.0f * u);           // inf-safe: e=inf -> th=1
    const float th = 1.0f - 2.0f / (e + 1.0f);
    return 0.5f * x * (1.0f + th);
}

// async global->LDS, 16B per lane (dest = wave-uniform base + lane*16)
__device__ __forceinline__ void gload_lds16(const bf16_t* g, bf16_t* l) {
    __builtin_amdgcn_global_load_lds(
        (__attribute__((address_space(1))) void*)(g),
        (__attribute__((address_space(3))) void*)(l), 16, 0, 0);
}

// ---------------- merged weight fp32 -> bf16 conversion (1 dispatch) --------
// region sizes fixed at compile time; all 1024-elem aligned.
__launch_bounds__(256)
__global__ void wconv_all(const float* __restrict__ w_in, const float* __restrict__ w_out,
                          const float* __restrict__ w_m1, const float* __restrict__ w_m2,
                          const float* __restrict__ w_dt, const float* __restrict__ w_xp,
                          bf16_t* __restrict__ ws) {
    const int blk = blockIdx.x;
    const int li = threadIdx.x * 4;
    float v[4] = {0.f, 0.f, 0.f, 0.f};
    if (blk < 4096) {            // in_proj 4096x1024
        const size_t i = (size_t)blk * 1024 + li;
        ld4(w_in + i, v);  st4(ws + WS_WIN + i, v);
    } else if (blk < 6144) {     // out_proj 1024x2048
        const size_t i = (size_t)(blk - 4096) * 1024 + li;
        ld4(w_out + i, v); st4(ws + WS_WOUT + i, v);
    } else if (blk < 8192) {     // mlp_w1 2048x1024
        const size_t i = (size_t)(blk - 6144) * 1024 + li;
        ld4(w_m1 + i, v);  st4(ws + WS_WM1 + i, v);
    } else if (blk < 10240) {    // mlp_w2 1024x2048
        const size_t i = (size_t)(blk - 8192) * 1024 + li;
        ld4(w_m2 + i, v);  st4(ws + WS_WM2 + i, v);
    } else if (blk < 10368) {    // dt_proj 2048x64
        const size_t i = (size_t)(blk - 10240) * 1024 + li;
        ld4(w_dt + i, v);  st4(ws + WS_WDT + i, v);
    } else {                     // x_proj padded 128x2048 (src 96x2048)
        const size_t i = (size_t)(blk - 10368) * 1024 + li;
        if (i < 96u * 2048u) ld4(w_xp + i, v);
        st4(ws + WS_WXP + i, v);
    }
}

// ---------------- LayerNorm (row = 1024): T in, bf16 out ----------------
template <typename T>
__launch_bounds__(256)
__global__ void ln_kernel(const T* __restrict__ x, const float* __restrict__ g,
                          const float* __restrict__ b, bf16_t* __restrict__ out) {
    const int row = blockIdx.x;
    float v[4];
    ld4(x + (size_t)row * D_MODEL + threadIdx.x * 4, v);
    float s = v[0] + v[1] + v[2] + v[3];
    float s2 = v[0] * v[0] + v[1] * v[1] + v[2] * v[2] + v[3] * v[3];
    for (int off = 32; off > 0; off >>= 1) {
        s += __shfl_down(s, off);
        s2 += __shfl_down(s2, off);
    }
    __shared__ float ls[4], ls2[4];
    const int wid = threadIdx.x >> 6;
    if ((threadIdx.x & 63) == 0) { ls[wid] = s; ls2[wid] = s2; }
    __syncthreads();
    const float ts = ls[0] + ls[1] + ls[2] + ls[3];
    const float ts2 = ls2[0] + ls2[1] + ls2[2] + ls2[3];
    const float mean = ts * (1.0f / D_MODEL);
    const float var = ts2 * (1.0f / D_MODEL) - mean * mean;
    const float inv = rsqrtf(var + 1e-5f);
    float gg[4], bb[4], o[4];
    ld4(g + threadIdx.x * 4, gg);
    ld4(b + threadIdx.x * 4, bb);
    for (int i = 0; i < 4; ++i) o[i] = (v[i] - mean) * inv * gg[i] + bb[i];
    st4(out + (size_t)row * D_MODEL + threadIdx.x * 4, o);
}

// ---------------- MFMA GEMM: out[M,N] = A[M,K] @ W[N,K]^T (+epilogue) -------
// A, W bf16; 128x128 tile, BK=32, 4 waves (2x2), 4x4 mfma_16x16x32 per wave.
// EPI: 0=none, 1=bias+softplus, 2=bias+gelu, 3=+res, 4=bias+res
template <int EPI, typename RT, typename OT>
__launch_bounds__(256)
__global__ void mfma_gemm(const bf16_t* __restrict__ A, int lda,
                          const bf16_t* __restrict__ W, int ldw,
                          const float* __restrict__ bias,
                          const RT* __restrict__ res, int ldr,
                          OT* __restrict__ out, int ldo, int nstore,
                          int K) {
    __shared__ bf16_t As[128 * 32];  // [row][k] row-major, 8KB
    __shared__ bf16_t Ws[128 * 32];
    const int tid = threadIdx.x;
    const int lane = tid & 63;
    const int wv = tid >> 6;
    const int wm = (wv & 1) * 64;
    const int wn = (wv >> 1) * 64;
    const int fr = lane & 15;   // fragment row (m or n)
    const int fq = lane >> 4;   // quad: k = fq*8+j ; C/D row = fq*4+r
    const int m0 = blockIdx.y * 128;
    const int n0 = blockIdx.x * 128;

    float4v acc[4][4] = {};

    for (int k0 = 0; k0 < K; k0 += 32) {
#pragma unroll
        for (int q = 0; q < 2; ++q) {
            const int e = q * 256 + tid;  // 0..511 ; row=e>>2, seg=e&3
            gload_lds16(A + (size_t)(m0 + (e >> 2)) * lda + k0 + (e & 3) * 8, &As[e * 8]);
        }
#pragma unroll
        for (int q = 0; q < 2; ++q) {
            const int e = q * 256 + tid;
            gload_lds16(W + (size_t)(n0 + (e >> 2)) * ldw + k0 + (e & 3) * 8, &Ws[e * 8]);
        }
        __syncthreads();  // drains global_load_lds (vmcnt) + makes LDS visible
        short8v a[4], b[4];
#pragma unroll
        for (int i = 0; i < 4; ++i)
            a[i] = *(const short8v*)&As[(wm + i * 16 + fr) * 32 + fq * 8];
#pragma unroll
        for (int j = 0; j < 4; ++j)
            b[j] = *(const short8v*)&Ws[(wn + j * 16 + fr) * 32 + fq * 8];
#pragma unroll
        for (int i = 0; i < 4; ++i)
#pragma unroll
            for (int j = 0; j < 4; ++j)
                acc[i][j] = __builtin_amdgcn_mfma_f32_16x16x32_bf16(a[i], b[j], acc[i][j], 0, 0, 0);
        __syncthreads();  // protect LDS from next iteration's staging
    }

    // epilogue: C/D mapping col=lane&15, row=(lane>>4)*4+reg  [m89-verified]
#pragma unroll
    for (int i = 0; i < 4; ++i) {
#pragma unroll
        for (int j = 0; j < 4; ++j) {
            const int col = n0 + wn + j * 16 + fr;
            if (col < nstore) {
#pragma unroll
                for (int r = 0; r < 4; ++r) {
                    const int row = m0 + wm + i * 16 + fq * 4 + r;
                    float v = acc[i][j][r];
                    if (EPI == 1 || EPI == 2 || EPI == 4) v += bias[col];
                    if (EPI == 1) v = softplusf_(v);
                    if (EPI == 2) v = geluf_(v);
                    if (EPI == 3 || EPI == 4) v += ld1(res + (size_t)row * ldr + col);
                    st1(out + (size_t)row * ldo + col, v);
                }
            }
        }
    }
}

// ---------------- x_proj split-K GEMM: part[ks] = xa[:,ks*512:+512] @ Wxp^T --
// M=8192, Npad=128, Kslice=512; grid (4, 64); fp32 partial out.
__launch_bounds__(256)
__global__ void xproj_gemm(const bf16_t* __restrict__ Ab, const bf16_t* __restrict__ Wb,
                           float* __restrict__ part) {
    __shared__ bf16_t As[128 * 32];
    __shared__ bf16_t Ws[128 * 32];
    const int ks = blockIdx.x;
    const bf16_t* A = Ab + ks * 512;
    const bf16_t* W = Wb + ks * 512;
    float* out = part + (size_t)ks * NTOK * 128;
    const int tid = threadIdx.x;
    const int lane = tid & 63;
    const int wv = tid >> 6;
    const int wm = (wv & 1) * 64;
    const int wn = (wv >> 1) * 64;
    const int fr = lane & 15;
    const int fq = lane >> 4;
    const int m0 = blockIdx.y * 128;

    float4v acc[4][4] = {};
    for (int k0 = 0; k0 < 512; k0 += 32) {
#pragma unroll
        for (int q = 0; q < 2; ++q) {
            const int e = q * 256 + tid;
            gload_lds16(A + (size_t)(m0 + (e >> 2)) * 2048 + k0 + (e & 3) * 8, &As[e * 8]);
        }
#pragma unroll
        for (int q = 0; q < 2; ++q) {
            const int e = q * 256 + tid;
            gload_lds16(W + (size_t)(e >> 2) * 2048 + k0 + (e & 3) * 8, &Ws[e * 8]);
        }
        __syncthreads();
        short8v a[4], b[4];
#pragma unroll
        for (int i = 0; i < 4; ++i)
            a[i] = *(const short8v*)&As[(wm + i * 16 + fr) * 32 + fq * 8];
#pragma unroll
        for (int j = 0; j < 4; ++j)
            b[j] = *(const short8v*)&Ws[(wn + j * 16 + fr) * 32 + fq * 8];
#pragma unroll
        for (int i = 0; i < 4; ++i)
#pragma unroll
            for (int j = 0; j < 4; ++j)
                acc[i][j] = __builtin_amdgcn_mfma_f32_16x16x32_bf16(a[i], b[j], acc[i][j], 0, 0, 0);
        __syncthreads();
    }
#pragma unroll
    for (int i = 0; i < 4; ++i)
#pragma unroll
        for (int j = 0; j < 4; ++j) {
            const int col = wn + j * 16 + fr;
#pragma unroll
            for (int r = 0; r < 4; ++r) {
                const int row = m0 + wm + i * 16 + fq * 4 + r;
                out[(size_t)row * 128 + col] = acc[i][j][r];
            }
        }
}

// reduce 4 fp32 partials -> bf16 xdbl (ld 96); 8192*24 threads, 4 cols each
__launch_bounds__(256)
__global__ void xproj_reduce(const float* __restrict__ part, bf16_t* __restrict__ xdbl) {
    const int idx = blockIdx.x * 256 + threadIdx.x;  // 196608
    const int t = idx / 24;
    const int c4 = (idx - t * 24) * 4;
    float s[4] = {0.f, 0.f, 0.f, 0.f};
#pragma unroll
    for (int ks = 0; ks < 4; ++ks) {
        float v[4];
        ld4(part + (size_t)ks * NTOK * 128 + (size_t)t * 128 + c4, v);
        s[0] += v[0]; s[1] += v[1]; s[2] += v[2]; s[3] += v[3];
    }
    st4(xdbl + (size_t)t * 96 + c4, s);
}

// ---------------- causal depthwise conv (k=4) + SiLU, 4 d per thread --------
__launch_bounds__(256)
__global__ void conv_silu_kernel(const bf16_t* __restrict__ xm, const float* __restrict__ cw,
                                 const float* __restrict__ cb, bf16_t* __restrict__ xa) {
    const int idx = blockIdx.x * 256 + threadIdx.x;  // over NTOK * 512
    const int d4 = (idx & 511) * 4;
    const int bt = idx >> 9;
    const int t = bt & (LL - 1);
    const int b = bt >> 11;
    float acc[4];
    ld4(cb + d4, acc);
    float w[4][4];
#pragma unroll
    for (int j = 0; j < 4; ++j) ld4(cw + (d4 + j) * 4, w[j]);
#pragma unroll
    for (int k = 0; k < D_CONVK; ++k) {
        const int tt = t - 3 + k;
        if (tt >= 0) {
            float xv[4];
            ld4(xm + ((size_t)(b * LL + tt)) * 2048 + d4, xv);
#pragma unroll
            for (int j = 0; j < 4; ++j) acc[j] += xv[j] * w[j][k];
        }
    }
    float o[4];
#pragma unroll
    for (int j = 0; j < 4; ++j) o[j] = siluf_(acc[j]);
    st4(xa + (size_t)bt * 2048 + d4, o);
}

// ---------------- selective scan: segmented two-pass, 16 states/thread ------
__launch_bounds__(256)
__global__ void scan_pass1(const bf16_t* __restrict__ delta,  // ld 2048
                           const bf16_t* __restrict__ xa,     // ld 2048
                           const bf16_t* __restrict__ xdbl,   // ld 96
                           const float* __restrict__ A_log,
                           float* __restrict__ Pbuf, float* __restrict__ Hbuf) {
    const int bs = blockIdx.x;  // b*NSEG + s
    const int b = bs >> 4, s = bs & 15;
    const int d = blockIdx.y * 256 + threadIdx.x;
    float Ac[16], h[16], P[16];
#pragma unroll
    for (int n = 0; n < 16; ++n) {
        Ac[n] = -__expf(A_log[d * 16 + n]);
        h[n] = 0.f;
        P[n] = 1.f;
    }
    const size_t tokbase = (size_t)b * LL + s * TSEG;
    float dlt, u;
    ushort8v B0, B1;
    {
        const size_t tok = tokbase;
        dlt = b2f(delta[tok * 2048 + d]);
        u = b2f(xa[tok * 2048 + d]);
        B0 = *(const ushort8v*)&xdbl[tok * 96 + 64];
        B1 = *(const ushort8v*)&xdbl[tok * 96 + 72];
    }
    for (int t = 0; t < TSEG; ++t) {
        const int tn = (t + 1 < TSEG) ? t + 1 : t;
        const size_t tok = tokbase + tn;
        const float dltn = b2f(delta[tok * 2048 + d]);
        const float un = b2f(xa[tok * 2048 + d]);
        const ushort8v B0n = *(const ushort8v*)&xdbl[tok * 96 + 64];
        const ushort8v B1n = *(const ushort8v*)&xdbl[tok * 96 + 72];
        float Bv[16];
        unpack8(B0, Bv);
        unpack8(B1, Bv + 8);
        const float s0 = dlt * u;
#pragma unroll
        for (int n = 0; n < 16; ++n) {
            const float dA = __expf(dlt * Ac[n]);
            P[n] *= dA;
            h[n] = h[n] * dA + s0 * Bv[n];
        }
        dlt = dltn; u = un; B0 = B0n; B1 = B1n;
    }
    const size_t ob = ((((size_t)b * NSEG + s) * 2048) + d) * 16;
#pragma unroll
    for (int q = 0; q < 4; ++q) {
        *(float4*)(Pbuf + ob + q * 4) = make_float4(P[q*4], P[q*4+1], P[q*4+2], P[q*4+3]);
        *(float4*)(Hbuf + ob + q * 4) = make_float4(h[q*4], h[q*4+1], h[q*4+2], h[q*4+3]);
    }
}

__launch_bounds__(256)
__global__ void scan_combine(const float* __restrict__ Pbuf, float* __restrict__ Hbuf) {
    const int tid = blockIdx.x * 256 + threadIdx.x;  // 131072 = 4b * 2048d * 16n
    const int n = tid & 15;
    const int d = (tid >> 4) & 2047;
    const int b = tid >> 15;
    float carry = 0.f;
    for (int s = 0; s < NSEG; ++s) {
        const size_t idx = ((((size_t)b * NSEG + s) * 2048) + d) * 16 + n;
        const float P = Pbuf[idx];
        const float Hp = Hbuf[idx];
        Hbuf[idx] = carry;            // h_init for segment s
        carry = Hp + P * carry;
    }
}

__launch_bounds__(256)
__global__ void scan_pass2(bf16_t* dy,                        // delta in / y out (ld 2048)
                           const bf16_t* __restrict__ xa,
                           const bf16_t* __restrict__ xdbl,
                           const bf16_t* __restrict__ z,      // ld 2048
                           const float* __restrict__ A_log,
                           const float* __restrict__ Dp,
                           const float* __restrict__ Hbuf) {
    const int bs = blockIdx.x;
    const int b = bs >> 4, s = bs & 15;
    const int d = blockIdx.y * 256 + threadIdx.x;
    float Ac[16], h[16];
    const size_t hb = ((((size_t)b * NSEG + s) * 2048) + d) * 16;
#pragma unroll
    for (int n = 0; n < 16; ++n) {
        Ac[n] = -__expf(A_log[d * 16 + n]);
        h[n] = Hbuf[hb + n];
    }
    const float Dd = Dp[d];
    const size_t tokbase = (size_t)b * LL + s * TSEG;
    float dlt, u, zz;
    ushort8v B0, B1, C0, C1;
    {
        const size_t tok = tokbase;
        dlt = b2f(dy[tok * 2048 + d]);
        u = b2f(xa[tok * 2048 + d]);
        zz = b2f(z[tok * 2048 + d]);
        B0 = *(const ushort8v*)&xdbl[tok * 96 + 64];
        B1 = *(const ushort8v*)&xdbl[tok * 96 + 72];
        C0 = *(const ushort8v*)&xdbl[tok * 96 + 80];
        C1 = *(const ushort8v*)&xdbl[tok * 96 + 88];
    }
    for (int t = 0; t < TSEG; ++t) {
        const int tn = (t + 1 < TSEG) ? t + 1 : t;
        const size_t tok = tokbase + tn;
        const float dltn = b2f(dy[tok * 2048 + d]);
        const float un = b2f(xa[tok * 2048 + d]);
        const float zzn = b2f(z[tok * 2048 + d]);
        const ushort8v B0n = *(const ushort8v*)&xdbl[tok * 96 + 64];
        const ushort8v B1n = *(const ushort8v*)&xdbl[tok * 96 + 72];
        const ushort8v C0n = *(const ushort8v*)&xdbl[tok * 96 + 80];
        const ushort8v C1n = *(const ushort8v*)&xdbl[tok * 96 + 88];
        float Bv[16], Cv[16];
        unpack8(B0, Bv); unpack8(B1, Bv + 8);
        unpack8(C0, Cv); unpack8(C1, Cv + 8);
        const float s0 = dlt * u;
        float y = 0.f;
#pragma unroll
        for (int n = 0; n < 16; ++n) {
            const float dA = __expf(dlt * Ac[n]);
            h[n] = h[n] * dA + s0 * Bv[n];
            y = fmaf(h[n], Cv[n], y);
        }
        y = (y + u * Dd) * siluf_(zz);
        dy[(tokbase + t) * 2048 + d] = f2b(y);  // after next-packet loads
        dlt = dltn; u = un; zz = zzn;
        B0 = B0n; B1 = B1n; C0 = C0n; C1 = C1n;
    }
}

// ---------------- launch ----------------
extern "C" void kernel_launch(void* const* d_in, const int* in_sizes, int n_in,
                              void* d_out, int out_size, void* d_ws, size_t ws_size,
                              hipStream_t stream) {
    const float* x         = (const float*)d_in[0];
    const float* ln1_g     = (const float*)d_in[1];
    const float* ln1_b     = (const float*)d_in[2];
    const float* in_proj_w = (const float*)d_in[3];
    const float* conv_w    = (const float*)d_in[4];
    const float* conv_b    = (const float*)d_in[5];
    const float* x_proj_w  = (const float*)d_in[6];
    const float* dt_proj_w = (const float*)d_in[7];
    const float* dt_proj_b = (const float*)d_in[8];
    const float* A_log     = (const float*)d_in[9];
    const float* Dp        = (const float*)d_in[10];
    const float* out_proj_w= (const float*)d_in[11];
    const float* ln2_g     = (const float*)d_in[12];
    const float* ln2_b     = (const float*)d_in[13];
    const float* mlp_w1    = (const float*)d_in[14];
    const float* mlp_b1    = (const float*)d_in[15];
    const float* mlp_w2    = (const float*)d_in[16];
    const float* mlp_b2    = (const float*)d_in[17];
    float* outp = (float*)d_out;

    bf16_t* ws    = (bf16_t*)d_ws;
    bf16_t* h     = ws + WS_H;     // NTOK x 1024; later h2
    bf16_t* xm    = ws + WS_XM;    // NTOK x 2048; later delta -> y -> m1
    bf16_t* z     = ws + WS_Z;     // NTOK x 2048
    bf16_t* xa    = ws + WS_XA;    // NTOK x 2048
    bf16_t* xdbl  = ws + WS_XDBL;  // NTOK x 96
    bf16_t* xres  = ws + WS_XRES;  // NTOK x 1024; aliases xp-partials then P/H
    bf16_t* wb_in = ws + WS_WIN;
    bf16_t* wb_out= ws + WS_WOUT;
    bf16_t* wb_m1 = ws + WS_WM1;
    bf16_t* wb_m2 = ws + WS_WM2;
    bf16_t* wb_dt = ws + WS_WDT;
    bf16_t* wb_xp = ws + WS_WXP;
    bf16_t* h2    = h;
    bf16_t* delta = xm;
    bf16_t* y     = xm;
    bf16_t* m1    = xm;
    float*  xpart = (float*)xres;            // 4 x NTOK x 128 fp32 (16.8 MB)
    float*  Pbuf  = (float*)xres;            // 2,097,152 floats (after xpart dead)
    float*  Hbuf  = Pbuf + 2097152;          // 2,097,152 floats

    // 0. all weight conversions in one dispatch
    wconv_all<<<10624, 256, 0, stream>>>(in_proj_w, out_proj_w, mlp_w1, mlp_w2,
                                         dt_proj_w, x_proj_w, ws);
    // 1. LN1 (fp32 in)
    ln_kernel<float><<<NTOK, 256, 0, stream>>>(x, ln1_g, ln1_b, h);
    // 2a. in_proj x-half: xm = h @ W[0:2048].T  (contiguous ld 2048)
    mfma_gemm<0, float, bf16_t><<<dim3(16, 64), 256, 0, stream>>>(
        h, D_MODEL, wb_in, D_MODEL, nullptr, (const float*)nullptr, 0, xm, 2048, 2048, D_MODEL);
    // 2b. in_proj z-half: z = h @ W[2048:4096].T
    mfma_gemm<0, float, bf16_t><<<dim3(16, 64), 256, 0, stream>>>(
        h, D_MODEL, wb_in + (size_t)D_INNER * D_MODEL, D_MODEL, nullptr,
        (const float*)nullptr, 0, z, 2048, 2048, D_MODEL);
    // 3. conv + silu -> xa
    conv_silu_kernel<<<(NTOK * 512) / 256, 256, 0, stream>>>(xm, conv_w, conv_b, xa);
    // 4. x_proj split-K x4 -> fp32 partials -> reduce -> xdbl bf16
    xproj_gemm<<<dim3(4, 64), 256, 0, stream>>>(xa, wb_xp, xpart);
    xproj_reduce<<<(NTOK * 24) / 256, 256, 0, stream>>>(xpart, xdbl);
    // 5. dt_proj + softplus: delta = softplus(xdbl[:, :64] @ dt.T + b)  K=64
    mfma_gemm<1, float, bf16_t><<<dim3(16, 64), 256, 0, stream>>>(
        xdbl, 96, wb_dt, DT_RANK, dt_proj_b, (const float*)nullptr, 0, delta, 2048, 2048, DT_RANK);
    // 6. selective scan: pass1 / combine / pass2 (y over delta buffer)
    scan_pass1<<<dim3(BB * NSEG, D_INNER / 256), 256, 0, stream>>>(
        delta, xa, xdbl, A_log, Pbuf, Hbuf);
    scan_combine<<<(BB * D_INNER * D_STATE) / 256, 256, 0, stream>>>(Pbuf, Hbuf);
    scan_pass2<<<dim3(BB * NSEG, D_INNER / 256), 256, 0, stream>>>(
        xm, xa, xdbl, z, A_log, Dp, Hbuf);
    // 7. out_proj + residual x (fp32) -> xres   N=1024 K=2048
    mfma_gemm<3, float, bf16_t><<<dim3(8, 64), 256, 0, stream>>>(
        y, 2048, wb_out, D_INNER, nullptr, x, D_MODEL, xres, D_MODEL, D_MODEL, D_INNER);
    // 8. LN2 (bf16 in)
    ln_kernel<bf16_t><<<NTOK, 256, 0, stream>>>(xres, ln2_g, ln2_b, h2);
    // 9. mlp1 + gelu -> m1 (y dead)   N=2048 K=1024
    mfma_gemm<2, float, bf16_t><<<dim3(16, 64), 256, 0, stream>>>(
        h2, D_MODEL, wb_m1, D_MODEL, mlp_b1, (const float*)nullptr, 0, m1, 2048, 2048, D_MODEL);
    // 10. mlp2 + bias + residual xres -> out (fp32)   N=1024 K=2048
    mfma_gemm<4, bf16_t, float><<<dim3(8, 64), 256, 0, stream>>>(
        m1, 2048, wb_m2, MLP_HID, mlp_b2, xres, D_MODEL, outp, D_MODEL, D_MODEL, MLP_HID);
}

// Round 8
// 676.157 us; speedup vs baseline: 6.4018x; 1.0458x over previous
//
#include <hip/hip_runtime.h>
#include <math.h>

// Problem constants
#define D_MODEL 1024
#define D_STATE 16
#define D_CONVK 4
#define D_INNER 2048
#define DT_RANK 64
#define MLP_HID 2048
#define BB 4
#define LL 2048
#define NTOK (BB * LL)  // 8192
#define TSEG 64
#define NSEG 32

typedef unsigned short bf16_t;
typedef __attribute__((ext_vector_type(8))) short short8v;          // 8 bf16 (4 VGPRs)
typedef __attribute__((ext_vector_type(8))) unsigned short ushort8v;
typedef __attribute__((ext_vector_type(4))) float float4v;          // 4 fp32 acc

// workspace offsets (bf16 elems); total 78,774,272 = 157.5 MB (proven cap)
#define WS_H      0u
#define WS_XM     8388608u
#define WS_Z      25165824u
#define WS_XA     41943040u
#define WS_XDBL   58720256u
#define WS_XRES   59506688u
#define WS_WIN    67895296u
#define WS_WOUT   72089600u
#define WS_WM1    74186752u
#define WS_WM2    76283904u
#define WS_WDT    78381056u
#define WS_WXP    78512128u

#if __has_builtin(__builtin_amdgcn_exp2f)
#define EXP2F(x) __builtin_amdgcn_exp2f(x)
#else
#define EXP2F(x) exp2f(x)
#endif
#define LOG2E 1.4426950408889634f

// ---------------- dtype helpers ----------------
__device__ __forceinline__ float b2f(bf16_t u) {
    return __uint_as_float(((unsigned int)u) << 16);
}
__device__ __forceinline__ bf16_t f2b(float f) {
    unsigned int x = __float_as_uint(f);
    unsigned int r = (x + 0x7FFFu + ((x >> 16) & 1u)) >> 16;
    return (bf16_t)r;
}
__device__ __forceinline__ void ld4(const float* p, float v[4]) {
    const float4 t = *(const float4*)p;
    v[0] = t.x; v[1] = t.y; v[2] = t.z; v[3] = t.w;
}
__device__ __forceinline__ void ld4(const bf16_t* p, float v[4]) {
    const ushort4 t = *(const ushort4*)p;
    v[0] = b2f(t.x); v[1] = b2f(t.y); v[2] = b2f(t.z); v[3] = b2f(t.w);
}
__device__ __forceinline__ float ld1(const float* p) { return *p; }
__device__ __forceinline__ float ld1(const bf16_t* p) { return b2f(*p); }
__device__ __forceinline__ void st1(float* p, float v) { *p = v; }
__device__ __forceinline__ void st1(bf16_t* p, float v) { *p = f2b(v); }
__device__ __forceinline__ void st4(bf16_t* p, const float v[4]) {
    *(ushort4*)p = make_ushort4(f2b(v[0]), f2b(v[1]), f2b(v[2]), f2b(v[3]));
}
__device__ __forceinline__ void unpack8(ushort8v p, float* f) {
#pragma unroll
    for (int i = 0; i < 8; ++i) f[i] = b2f((bf16_t)p[i]);
}

__device__ __forceinline__ float sigmoidf_(float x) { return 1.0f / (1.0f + __expf(-x)); }
__device__ __forceinline__ float siluf_(float x) { return x * sigmoidf_(x); }
// fast branch-free softplus: max(x,0) + log(1+exp(-|x|)); v_exp/v_log HW ops
__device__ __forceinline__ float softplusf_(float x) {
    return fmaxf(x, 0.0f) + __logf(1.0f + __expf(-fabsf(x)));
}
// fast GELU (tanh form)
__device__ __forceinline__ float geluf_(float x) {
    const float u = 0.7978845608028654f * (x + 0.044715f * x * x * x);
    const float e = __expf(2.0f * u);           // inf-safe: e=inf -> th=1
    const float th = 1.0f - 2.0f / (e + 1.0f);
    return 0.5f * x * (1.0f + th);
}

// async global->LDS, 16B per lane (dest = wave-uniform base + lane*16)
__device__ __forceinline__ void gload_lds16(const bf16_t* g, bf16_t* l) {
    __builtin_amdgcn_global_load_lds(
        (__attribute__((address_space(1))) void*)(g),
        (__attribute__((address_space(3))) void*)(l), 16, 0, 0);
}

// ---------------- merged weight fp32 -> bf16 conversion (1 dispatch) --------
__launch_bounds__(256)
__global__ void wconv_all(const float* __restrict__ w_in, const float* __restrict__ w_out,
                          const float* __restrict__ w_m1, const float* __restrict__ w_m2,
                          const float* __restrict__ w_dt, const float* __restrict__ w_xp,
                          bf16_t* __restrict__ ws) {
    const int blk = blockIdx.x;
    const int li = threadIdx.x * 4;
    float v[4] = {0.f, 0.f, 0.f, 0.f};
    if (blk < 4096) {            // in_proj 4096x1024
        const size_t i = (size_t)blk * 1024 + li;
        ld4(w_in + i, v);  st4(ws + WS_WIN + i, v);
    } else if (blk < 6144) {     // out_proj 1024x2048
        const size_t i = (size_t)(blk - 4096) * 1024 + li;
        ld4(w_out + i, v); st4(ws + WS_WOUT + i, v);
    } else if (blk < 8192) {     // mlp_w1 2048x1024
        const size_t i = (size_t)(blk - 6144) * 1024 + li;
        ld4(w_m1 + i, v);  st4(ws + WS_WM1 + i, v);
    } else if (blk < 10240) {    // mlp_w2 1024x2048
        const size_t i = (size_t)(blk - 8192) * 1024 + li;
        ld4(w_m2 + i, v);  st4(ws + WS_WM2 + i, v);
    } else if (blk < 10368) {    // dt_proj 2048x64
        const size_t i = (size_t)(blk - 10240) * 1024 + li;
        ld4(w_dt + i, v);  st4(ws + WS_WDT + i, v);
    } else {                     // x_proj padded 128x2048 (src 96x2048)
        const size_t i = (size_t)(blk - 10368) * 1024 + li;
        if (i < 96u * 2048u) ld4(w_xp + i, v);
        st4(ws + WS_WXP + i, v);
    }
}

// ---------------- LayerNorm (row = 1024): T in, bf16 out ----------------
template <typename T>
__launch_bounds__(256)
__global__ void ln_kernel(const T* __restrict__ x, const float* __restrict__ g,
                          const float* __restrict__ b, bf16_t* __restrict__ out) {
    const int row = blockIdx.x;
    float v[4];
    ld4(x + (size_t)row * D_MODEL + threadIdx.x * 4, v);
    float s = v[0] + v[1] + v[2] + v[3];
    float s2 = v[0] * v[0] + v[1] * v[1] + v[2] * v[2] + v[3] * v[3];
    for (int off = 32; off > 0; off >>= 1) {
        s += __shfl_down(s, off);
        s2 += __shfl_down(s2, off);
    }
    __shared__ float ls[4], ls2[4];
    const int wid = threadIdx.x >> 6;
    if ((threadIdx.x & 63) == 0) { ls[wid] = s; ls2[wid] = s2; }
    __syncthreads();
    const float ts = ls[0] + ls[1] + ls[2] + ls[3];
    const float ts2 = ls2[0] + ls2[1] + ls2[2] + ls2[3];
    const float mean = ts * (1.0f / D_MODEL);
    const float var = ts2 * (1.0f / D_MODEL) - mean * mean;
    const float inv = rsqrtf(var + 1e-5f);
    float gg[4], bb[4], o[4];
    ld4(g + threadIdx.x * 4, gg);
    ld4(b + threadIdx.x * 4, bb);
    for (int i = 0; i < 4; ++i) o[i] = (v[i] - mean) * inv * gg[i] + bb[i];
    st4(out + (size_t)row * D_MODEL + threadIdx.x * 4, o);
}

// ---------------- MFMA GEMM: out[M,N] = A[M,K] @ W[N,K]^T (+epilogue) -------
// A, W bf16; 128x128 tile, BK=32, 4 waves (2x2), 4x4 mfma_16x16x32 per wave.
// EPI: 0=none, 1=bias+softplus, 2=bias+gelu, 3=+res, 4=bias+res
template <int EPI, typename RT, typename OT>
__launch_bounds__(256)
__global__ void mfma_gemm(const bf16_t* __restrict__ A, int lda,
                          const bf16_t* __restrict__ W, int ldw,
                          const float* __restrict__ bias,
                          const RT* __restrict__ res, int ldr,
                          OT* __restrict__ out, int ldo, int nstore,
                          int K) {
    __shared__ bf16_t As[128 * 32];  // [row][k] row-major, 8KB
    __shared__ bf16_t Ws[128 * 32];
    const int tid = threadIdx.x;
    const int lane = tid & 63;
    const int wv = tid >> 6;
    const int wm = (wv & 1) * 64;
    const int wn = (wv >> 1) * 64;
    const int fr = lane & 15;   // fragment row (m or n)
    const int fq = lane >> 4;   // quad: k = fq*8+j ; C/D row = fq*4+r
    const int m0 = blockIdx.y * 128;
    const int n0 = blockIdx.x * 128;

    float4v acc[4][4] = {};

    for (int k0 = 0; k0 < K; k0 += 32) {
#pragma unroll
        for (int q = 0; q < 2; ++q) {
            const int e = q * 256 + tid;  // 0..511 ; row=e>>2, seg=e&3
            gload_lds16(A + (size_t)(m0 + (e >> 2)) * lda + k0 + (e & 3) * 8, &As[e * 8]);
        }
#pragma unroll
        for (int q = 0; q < 2; ++q) {
            const int e = q * 256 + tid;
            gload_lds16(W + (size_t)(n0 + (e >> 2)) * ldw + k0 + (e & 3) * 8, &Ws[e * 8]);
        }
        __syncthreads();  // drains global_load_lds (vmcnt) + makes LDS visible
        short8v a[4], b[4];
#pragma unroll
        for (int i = 0; i < 4; ++i)
            a[i] = *(const short8v*)&As[(wm + i * 16 + fr) * 32 + fq * 8];
#pragma unroll
        for (int j = 0; j < 4; ++j)
            b[j] = *(const short8v*)&Ws[(wn + j * 16 + fr) * 32 + fq * 8];
#pragma unroll
        for (int i = 0; i < 4; ++i)
#pragma unroll
            for (int j = 0; j < 4; ++j)
                acc[i][j] = __builtin_amdgcn_mfma_f32_16x16x32_bf16(a[i], b[j], acc[i][j], 0, 0, 0);
        __syncthreads();  // protect LDS from next iteration's staging
    }

    // epilogue: C/D mapping col=lane&15, row=(lane>>4)*4+reg  [m89-verified]
#pragma unroll
    for (int i = 0; i < 4; ++i) {
#pragma unroll
        for (int j = 0; j < 4; ++j) {
            const int col = n0 + wn + j * 16 + fr;
            if (col < nstore) {
#pragma unroll
                for (int r = 0; r < 4; ++r) {
                    const int row = m0 + wm + i * 16 + fq * 4 + r;
                    float v = acc[i][j][r];
                    if (EPI == 1 || EPI == 2 || EPI == 4) v += bias[col];
                    if (EPI == 1) v = softplusf_(v);
                    if (EPI == 2) v = geluf_(v);
                    if (EPI == 3 || EPI == 4) v += ld1(res + (size_t)row * ldr + col);
                    st1(out + (size_t)row * ldo + col, v);
                }
            }
        }
    }
}

// ---------------- x_proj split-K GEMM: part[ks] = xa[:,ks*512:+512] @ Wxp^T --
__launch_bounds__(256)
__global__ void xproj_gemm(const bf16_t* __restrict__ Ab, const bf16_t* __restrict__ Wb,
                           float* __restrict__ part) {
    __shared__ bf16_t As[128 * 32];
    __shared__ bf16_t Ws[128 * 32];
    const int ks = blockIdx.x;
    const bf16_t* A = Ab + ks * 512;
    const bf16_t* W = Wb + ks * 512;
    float* out = part + (size_t)ks * NTOK * 128;
    const int tid = threadIdx.x;
    const int lane = tid & 63;
    const int wv = tid >> 6;
    const int wm = (wv & 1) * 64;
    const int wn = (wv >> 1) * 64;
    const int fr = lane & 15;
    const int fq = lane >> 4;
    const int m0 = blockIdx.y * 128;

    float4v acc[4][4] = {};
    for (int k0 = 0; k0 < 512; k0 += 32) {
#pragma unroll
        for (int q = 0; q < 2; ++q) {
            const int e = q * 256 + tid;
            gload_lds16(A + (size_t)(m0 + (e >> 2)) * 2048 + k0 + (e & 3) * 8, &As[e * 8]);
        }
#pragma unroll
        for (int q = 0; q < 2; ++q) {
            const int e = q * 256 + tid;
            gload_lds16(W + (size_t)(e >> 2) * 2048 + k0 + (e & 3) * 8, &Ws[e * 8]);
        }
        __syncthreads();
        short8v a[4], b[4];
#pragma unroll
        for (int i = 0; i < 4; ++i)
            a[i] = *(const short8v*)&As[(wm + i * 16 + fr) * 32 + fq * 8];
#pragma unroll
        for (int j = 0; j < 4; ++j)
            b[j] = *(const short8v*)&Ws[(wn + j * 16 + fr) * 32 + fq * 8];
#pragma unroll
        for (int i = 0; i < 4; ++i)
#pragma unroll
            for (int j = 0; j < 4; ++j)
                acc[i][j] = __builtin_amdgcn_mfma_f32_16x16x32_bf16(a[i], b[j], acc[i][j], 0, 0, 0);
        __syncthreads();
    }
#pragma unroll
    for (int i = 0; i < 4; ++i)
#pragma unroll
        for (int j = 0; j < 4; ++j) {
            const int col = wn + j * 16 + fr;
#pragma unroll
            for (int r = 0; r < 4; ++r) {
                const int row = m0 + wm + i * 16 + fq * 4 + r;
                out[(size_t)row * 128 + col] = acc[i][j][r];
            }
        }
}

// reduce 4 fp32 partials -> bf16 xdbl (ld 96); 8192*24 threads, 4 cols each
__launch_bounds__(256)
__global__ void xproj_reduce(const float* __restrict__ part, bf16_t* __restrict__ xdbl) {
    const int idx = blockIdx.x * 256 + threadIdx.x;  // 196608
    const int t = idx / 24;
    const int c4 = (idx - t * 24) * 4;
    float s[4] = {0.f, 0.f, 0.f, 0.f};
#pragma unroll
    for (int ks = 0; ks < 4; ++ks) {
        float v[4];
        ld4(part + (size_t)ks * NTOK * 128 + (size_t)t * 128 + c4, v);
        s[0] += v[0]; s[1] += v[1]; s[2] += v[2]; s[3] += v[3];
    }
    st4(xdbl + (size_t)t * 96 + c4, s);
}

// ---------------- causal depthwise conv (k=4) + SiLU, 4 d per thread --------
__launch_bounds__(256)
__global__ void conv_silu_kernel(const bf16_t* __restrict__ xm, const float* __restrict__ cw,
                                 const float* __restrict__ cb, bf16_t* __restrict__ xa) {
    const int idx = blockIdx.x * 256 + threadIdx.x;  // over NTOK * 512
    const int d4 = (idx & 511) * 4;
    const int bt = idx >> 9;
    const int t = bt & (LL - 1);
    const int b = bt >> 11;
    float acc[4];
    ld4(cb + d4, acc);
    float w[4][4];
#pragma unroll
    for (int j = 0; j < 4; ++j) ld4(cw + (d4 + j) * 4, w[j]);
#pragma unroll
    for (int k = 0; k < D_CONVK; ++k) {
        const int tt = t - 3 + k;
        if (tt >= 0) {
            float xv[4];
            ld4(xm + ((size_t)(b * LL + tt)) * 2048 + d4, xv);
#pragma unroll
            for (int j = 0; j < 4; ++j) acc[j] += xv[j] * w[j][k];
        }
    }
    float o[4];
#pragma unroll
    for (int j = 0; j < 4; ++j) o[j] = siluf_(acc[j]);
    st4(xa + (size_t)bt * 2048 + d4, o);
}

// ---------------- selective scan: segmented two-pass, 16 states/thread ------
// NSEG=32 segments of TSEG=64 -> 1024 blocks/pass (4 waves/SIMD).
// dA computed as exp2(dlt * Ac2[n]) with Ac2 = -exp(A_log)*log2e (1 mul + v_exp).
__launch_bounds__(256)
__global__ void scan_pass1(const bf16_t* __restrict__ delta,  // ld 2048
                           const bf16_t* __restrict__ xa,     // ld 2048
                           const bf16_t* __restrict__ xdbl,   // ld 96
                           const float* __restrict__ A_log,
                           float* __restrict__ Pbuf, float* __restrict__ Hbuf) {
    const int bs = blockIdx.x;  // b*NSEG + s
    const int b = bs >> 5, s = bs & 31;
    const int d = blockIdx.y * 256 + threadIdx.x;
    float Ac[16], h[16], P[16];
#pragma unroll
    for (int n = 0; n < 16; ++n) {
        Ac[n] = -__expf(A_log[d * 16 + n]) * LOG2E;
        h[n] = 0.f;
        P[n] = 1.f;
    }
    const size_t tokbase = (size_t)b * LL + s * TSEG;
    float dlt, u;
    ushort8v B0, B1;
    {
        const size_t tok = tokbase;
        dlt = b2f(delta[tok * 2048 + d]);
        u = b2f(xa[tok * 2048 + d]);
        B0 = *(const ushort8v*)&xdbl[tok * 96 + 64];
        B1 = *(const ushort8v*)&xdbl[tok * 96 + 72];
    }
    for (int t = 0; t < TSEG; ++t) {
        const int tn = (t + 1 < TSEG) ? t + 1 : t;
        const size_t tok = tokbase + tn;
        const float dltn = b2f(delta[tok * 2048 + d]);
        const float un = b2f(xa[tok * 2048 + d]);
        const ushort8v B0n = *(const ushort8v*)&xdbl[tok * 96 + 64];
        const ushort8v B1n = *(const ushort8v*)&xdbl[tok * 96 + 72];
        float Bv[16];
        unpack8(B0, Bv);
        unpack8(B1, Bv + 8);
        const float s0 = dlt * u;
#pragma unroll
        for (int n = 0; n < 16; ++n) {
            const float dA = EXP2F(dlt * Ac[n]);
            P[n] *= dA;
            h[n] = h[n] * dA + s0 * Bv[n];
        }
        dlt = dltn; u = un; B0 = B0n; B1 = B1n;
    }
    const size_t ob = ((((size_t)b * NSEG + s) * 2048) + d) * 16;
#pragma unroll
    for (int q = 0; q < 4; ++q) {
        *(float4*)(Pbuf + ob + q * 4) = make_float4(P[q*4], P[q*4+1], P[q*4+2], P[q*4+3]);
        *(float4*)(Hbuf + ob + q * 4) = make_float4(h[q*4], h[q*4+1], h[q*4+2], h[q*4+3]);
    }
}

__launch_bounds__(256)
__global__ void scan_combine(const float* __restrict__ Pbuf, float* __restrict__ Hbuf) {
    const int tid = blockIdx.x * 256 + threadIdx.x;  // 131072 = 4b * 2048d * 16n
    const int n = tid & 15;
    const int d = (tid >> 4) & 2047;
    const int b = tid >> 15;
    float carry = 0.f;
    for (int s = 0; s < NSEG; ++s) {
        const size_t idx = ((((size_t)b * NSEG + s) * 2048) + d) * 16 + n;
        const float P = Pbuf[idx];
        const float Hp = Hbuf[idx];
        Hbuf[idx] = carry;            // h_init for segment s
        carry = Hp + P * carry;
    }
}

__launch_bounds__(256)
__global__ void scan_pass2(bf16_t* dy,                        // delta in / y out (ld 2048)
                           const bf16_t* __restrict__ xa,
                           const bf16_t* __restrict__ xdbl,
                           const bf16_t* __restrict__ z,      // ld 2048
                           const float* __restrict__ A_log,
                           const float* __restrict__ Dp,
                           const float* __restrict__ Hbuf) {
    const int bs = blockIdx.x;
    const int b = bs >> 5, s = bs & 31;
    const int d = blockIdx.y * 256 + threadIdx.x;
    float Ac[16], h[16];
    const size_t hb = ((((size_t)b * NSEG + s) * 2048) + d) * 16;
#pragma unroll
    for (int n = 0; n < 16; ++n) {
        Ac[n] = -__expf(A_log[d * 16 + n]) * LOG2E;
        h[n] = Hbuf[hb + n];
    }
    const float Dd = Dp[d];
    const size_t tokbase = (size_t)b * LL + s * TSEG;
    float dlt, u, zz;
    ushort8v B0, B1, C0, C1;
    {
        const size_t tok = tokbase;
        dlt = b2f(dy[tok * 2048 + d]);
        u = b2f(xa[tok * 2048 + d]);
        zz = b2f(z[tok * 2048 + d]);
        B0 = *(const ushort8v*)&xdbl[tok * 96 + 64];
        B1 = *(const ushort8v*)&xdbl[tok * 96 + 72];
        C0 = *(const ushort8v*)&xdbl[tok * 96 + 80];
        C1 = *(const ushort8v*)&xdbl[tok * 96 + 88];
    }
    for (int t = 0; t < TSEG; ++t) {
        const int tn = (t + 1 < TSEG) ? t + 1 : t;
        const size_t tok = tokbase + tn;
        const float dltn = b2f(dy[tok * 2048 + d]);
        const float un = b2f(xa[tok * 2048 + d]);
        const float zzn = b2f(z[tok * 2048 + d]);
        const ushort8v B0n = *(const ushort8v*)&xdbl[tok * 96 + 64];
        const ushort8v B1n = *(const ushort8v*)&xdbl[tok * 96 + 72];
        const ushort8v C0n = *(const ushort8v*)&xdbl[tok * 96 + 80];
        const ushort8v C1n = *(const ushort8v*)&xdbl[tok * 96 + 88];
        float Bv[16], Cv[16];
        unpack8(B0, Bv); unpack8(B1, Bv + 8);
        unpack8(C0, Cv); unpack8(C1, Cv + 8);
        const float s0 = dlt * u;
        float y = 0.f;
#pragma unroll
        for (int n = 0; n < 16; ++n) {
            const float dA = EXP2F(dlt * Ac[n]);
            h[n] = h[n] * dA + s0 * Bv[n];
            y = fmaf(h[n], Cv[n], y);
        }
        y = (y + u * Dd) * siluf_(zz);
        dy[(tokbase + t) * 2048 + d] = f2b(y);  // after next-packet loads
        dlt = dltn; u = un; zz = zzn;
        B0 = B0n; B1 = B1n; C0 = C0n; C1 = C1n;
    }
}

// ---------------- launch ----------------
extern "C" void kernel_launch(void* const* d_in, const int* in_sizes, int n_in,
                              void* d_out, int out_size, void* d_ws, size_t ws_size,
                              hipStream_t stream) {
    const float* x         = (const float*)d_in[0];
    const float* ln1_g     = (const float*)d_in[1];
    const float* ln1_b     = (const float*)d_in[2];
    const float* in_proj_w = (const float*)d_in[3];
    const float* conv_w    = (const float*)d_in[4];
    const float* conv_b    = (const float*)d_in[5];
    const float* x_proj_w  = (const float*)d_in[6];
    const float* dt_proj_w = (const float*)d_in[7];
    const float* dt_proj_b = (const float*)d_in[8];
    const float* A_log     = (const float*)d_in[9];
    const float* Dp        = (const float*)d_in[10];
    const float* out_proj_w= (const float*)d_in[11];
    const float* ln2_g     = (const float*)d_in[12];
    const float* ln2_b     = (const float*)d_in[13];
    const float* mlp_w1    = (const float*)d_in[14];
    const float* mlp_b1    = (const float*)d_in[15];
    const float* mlp_w2    = (const float*)d_in[16];
    const float* mlp_b2    = (const float*)d_in[17];
    float* outp = (float*)d_out;

    bf16_t* ws    = (bf16_t*)d_ws;
    bf16_t* h     = ws + WS_H;     // NTOK x 1024; dead during scan (Pbuf); later h2
    bf16_t* xm    = ws + WS_XM;    // NTOK x 2048; later delta -> y -> m1
    bf16_t* z     = ws + WS_Z;     // NTOK x 2048
    bf16_t* xa    = ws + WS_XA;    // NTOK x 2048
    bf16_t* xdbl  = ws + WS_XDBL;  // NTOK x 96
    bf16_t* xres  = ws + WS_XRES;  // NTOK x 1024; aliases xpart then Hbuf
    bf16_t* wb_in = ws + WS_WIN;
    bf16_t* wb_out= ws + WS_WOUT;
    bf16_t* wb_m1 = ws + WS_WM1;
    bf16_t* wb_m2 = ws + WS_WM2;
    bf16_t* wb_dt = ws + WS_WDT;
    bf16_t* wb_xp = ws + WS_WXP;
    bf16_t* h2    = h;
    bf16_t* delta = xm;
    bf16_t* y     = xm;
    bf16_t* m1    = xm;
    float*  xpart = (float*)xres;            // 4 x NTOK x 128 fp32 (16.8 MB)
    float*  Pbuf  = (float*)h;               // 4,194,304 floats (h dead during scan)
    float*  Hbuf  = (float*)xres;            // 4,194,304 floats (xpart dead by then)

    // 0. all weight conversions in one dispatch
    wconv_all<<<10624, 256, 0, stream>>>(in_proj_w, out_proj_w, mlp_w1, mlp_w2,
                                         dt_proj_w, x_proj_w, ws);
    // 1. LN1 (fp32 in)
    ln_kernel<float><<<NTOK, 256, 0, stream>>>(x, ln1_g, ln1_b, h);
    // 2a. in_proj x-half: xm = h @ W[0:2048].T  (contiguous ld 2048)
    mfma_gemm<0, float, bf16_t><<<dim3(16, 64), 256, 0, stream>>>(
        h, D_MODEL, wb_in, D_MODEL, nullptr, (const float*)nullptr, 0, xm, 2048, 2048, D_MODEL);
    // 2b. in_proj z-half: z = h @ W[2048:4096].T
    mfma_gemm<0, float, bf16_t><<<dim3(16, 64), 256, 0, stream>>>(
        h, D_MODEL, wb_in + (size_t)D_INNER * D_MODEL, D_MODEL, nullptr,
        (const float*)nullptr, 0, z, 2048, 2048, D_MODEL);
    // 3. conv + silu -> xa
    conv_silu_kernel<<<(NTOK * 512) / 256, 256, 0, stream>>>(xm, conv_w, conv_b, xa);
    // 4. x_proj split-K x4 -> fp32 partials -> reduce -> xdbl bf16
    xproj_gemm<<<dim3(4, 64), 256, 0, stream>>>(xa, wb_xp, xpart);
    xproj_reduce<<<(NTOK * 24) / 256, 256, 0, stream>>>(xpart, xdbl);
    // 5. dt_proj + softplus: delta = softplus(xdbl[:, :64] @ dt.T + b)  K=64
    mfma_gemm<1, float, bf16_t><<<dim3(16, 64), 256, 0, stream>>>(
        xdbl, 96, wb_dt, DT_RANK, dt_proj_b, (const float*)nullptr, 0, delta, 2048, 2048, DT_RANK);
    // 6. selective scan: pass1 / combine / pass2 (y over delta buffer)
    scan_pass1<<<dim3(BB * NSEG, D_INNER / 256), 256, 0, stream>>>(
        delta, xa, xdbl, A_log, Pbuf, Hbuf);
    scan_combine<<<(BB * D_INNER * D_STATE) / 256, 256, 0, stream>>>(Pbuf, Hbuf);
    scan_pass2<<<dim3(BB * NSEG, D_INNER / 256), 256, 0, stream>>>(
        xm, xa, xdbl, z, A_log, Dp, Hbuf);
    // 7. out_proj + residual x (fp32) -> xres   N=1024 K=2048
    mfma_gemm<3, float, bf16_t><<<dim3(8, 64), 256, 0, stream>>>(
        y, 2048, wb_out, D_INNER, nullptr, x, D_MODEL, xres, D_MODEL, D_MODEL, D_INNER);
    // 8. LN2 (bf16 in)
    ln_kernel<bf16_t><<<NTOK, 256, 0, stream>>>(xres, ln2_g, ln2_b, h2);
    // 9. mlp1 + gelu -> m1 (y dead)   N=2048 K=1024
    mfma_gemm<2, float, bf16_t><<<dim3(16, 64), 256, 0, stream>>>(
        h2, D_MODEL, wb_m1, D_MODEL, mlp_b1, (const float*)nullptr, 0, m1, 2048, 2048, D_MODEL);
    // 10. mlp2 + bias + residual xres -> out (fp32)   N=1024 K=2048
    mfma_gemm<4, bf16_t, float><<<dim3(8, 64), 256, 0, stream>>>(
        m1, 2048, wb_m2, MLP_HID, mlp_b2, xres, D_MODEL, outp, D_MODEL, D_MODEL, MLP_HID);
}